// Round 14
// baseline (248.869 us; speedup 1.0000x reference)
//
#include <hip/hip_runtime.h>
#include <hip/hip_fp16.h>
#include <math.h>

#define PI_F 3.14159265358979323846f

// ---------- complex helpers ----------
__device__ __forceinline__ float2 cadd(float2 a, float2 b){ return make_float2(a.x+b.x, a.y+b.y); }
__device__ __forceinline__ float2 csub(float2 a, float2 b){ return make_float2(a.x-b.x, a.y-b.y); }
__device__ __forceinline__ float2 cmul(float2 a, float2 b){ return make_float2(a.x*b.x - a.y*b.y, a.x*b.y + a.y*b.x); }
__device__ __forceinline__ float2 cscale(float2 a, float s){ return make_float2(a.x*s, a.y*s); }
__device__ __forceinline__ float2 cconj(float2 a){ return make_float2(a.x, -a.y); }
__device__ __forceinline__ float clip01(float v){ return fminf(fmaxf(v, 0.0f), 1.0f); }

// force block-uniform float into an SGPR
__device__ __forceinline__ float uniformf(float v){
  return __int_as_float(__builtin_amdgcn_readfirstlane(__float_as_int(v)));
}

// packed half mag/phase
__device__ __forceinline__ unsigned packmp(float mg, float ph){
  return ((unsigned)__half_as_ushort(__float2half_rn(ph)) << 16) |
          (unsigned)__half_as_ushort(__float2half_rn(mg));
}
__device__ __forceinline__ float mp_mag(unsigned u){
  return __half2float(__ushort_as_half((unsigned short)(u & 0xFFFFu)));
}
__device__ __forceinline__ float mp_ph(unsigned u){
  return __half2float(__ushort_as_half((unsigned short)(u >> 16)));
}

// LDS bank swizzles
__device__ __forceinline__ int swz14(int p){ return p ^ (15 & ((p>>4) ^ (p>>8) ^ (p>>12))); }
__device__ __forceinline__ int swz8 (int p){ return p ^ ((p>>4) & 15); }

// base-4 digit reversal
__device__ __forceinline__ int dr14(int k){
  unsigned x = __brev((unsigned)k) >> 18;
  return (int)(((x & 0x1555u) << 1) | ((x >> 1) & 0x1555u));
}
__device__ __forceinline__ int dr8(int k){
  unsigned x = __brev((unsigned)k) >> 24;
  return (int)(((x & 0x55u) << 1) | ((x >> 1) & 0x55u));
}

// Real-FFT unpack / repack
__device__ __forceinline__ void unpack_pair(float2 Zk, float2 Zm, float sn, float cs,
                                            float2& Uk, float2& Um) {
  float2 A  = make_float2(0.5f*(Zk.x+Zm.x), 0.5f*(Zk.y-Zm.y));
  float2 B  = make_float2(Zk.x-Zm.x, Zk.y+Zm.y);
  Uk = cadd(A, cmul(B, make_float2(-0.5f*sn, -0.5f*cs)));
  float2 Bm = make_float2(-B.x, B.y);
  Um = cadd(make_float2(A.x, -A.y), cmul(Bm, make_float2(-0.5f*sn, 0.5f*cs)));
}
__device__ __forceinline__ void repack_pair(float2 Vk, float2 Vm, float sn, float cs,
                                            float2& Wk, float2& Wm) {
  float2 P = make_float2(Vk.x+Vm.x, Vk.y-Vm.y);
  float2 Q = make_float2(Vk.x-Vm.x, Vk.y+Vm.y);
  Wk = cscale(cadd(P, cmul(Q, make_float2(-sn, cs))), 0.5f);
  float2 Qm = make_float2(-Q.x, Q.y);
  Wm = cscale(cadd(make_float2(P.x, -P.y), cmul(Qm, make_float2(-sn, -cs))), 0.5f);
}

__device__ __forceinline__ float sshape(int k, const float* ncs) {
  float pos = ((float)k + 0.5f) * (16.0f/16385.0f) - 0.5f;
  pos = fminf(fmaxf(pos, 0.0f), 15.0f);
  float fi = floorf(pos);
  int i0 = (int)fi;
  int i1 = min(i0 + 1, 15);
  float w = pos - fi;
  return ncs[i0]*(1.0f-w) + ncs[i1]*w;
}

#define LGKM() asm volatile("s_waitcnt lgkmcnt(0)" ::: "memory")

// ---- radix-4 butterflies, big buffer (swz14) ----
__device__ __forceinline__ void big_stage_fwd(float2* Cb, int u, int J, int lj) {
  int j = u & (J-1);
  int base = ((u >> lj) << (lj+2)) | j;
  float2 a0 = Cb[swz14(base)];
  float2 a1 = Cb[swz14(base+J)];
  float2 a2 = Cb[swz14(base+2*J)];
  float2 a3 = Cb[swz14(base+3*J)];
  float sn, cs; __sincosf((float)j * (-PI_F/(2.0f*(float)J)), &sn, &cs);
  float2 w1 = make_float2(cs, sn), w2 = cmul(w1,w1), w3 = cmul(w2,w1);
  float2 t0 = cadd(a0,a2), t1 = cadd(a1,a3), t2 = csub(a0,a2), t3 = csub(a1,a3);
  float2 mi = make_float2(t3.y, -t3.x);
  Cb[swz14(base)]     = cadd(t0,t1);
  Cb[swz14(base+J)]   = cmul(cadd(t2,mi), w1);
  Cb[swz14(base+2*J)] = cmul(csub(t0,t1), w2);
  Cb[swz14(base+3*J)] = cmul(csub(t2,mi), w3);
}
__device__ __forceinline__ void big_stage_inv(float2* Cb, int u, int J, int lj) {
  int j = u & (J-1);
  int base = ((u >> lj) << (lj+2)) | j;
  float sn, cs; __sincosf((float)j * (PI_F/(2.0f*(float)J)), &sn, &cs);
  float2 v1 = make_float2(cs, sn), v2 = cmul(v1,v1), v3 = cmul(v2,v1);
  float2 b0 = Cb[swz14(base)];
  float2 b1 = cmul(Cb[swz14(base+J)],   v1);
  float2 b2 = cmul(Cb[swz14(base+2*J)], v2);
  float2 b3 = cmul(Cb[swz14(base+3*J)], v3);
  float2 s02 = cadd(b0,b2), d02 = csub(b0,b2), s13 = cadd(b1,b3), d13 = csub(b1,b3);
  float2 id13 = make_float2(-d13.y, d13.x);
  Cb[swz14(base)]     = cadd(s02, s13);
  Cb[swz14(base+J)]   = cadd(d02, id13);
  Cb[swz14(base+2*J)] = csub(s02, s13);
  Cb[swz14(base+3*J)] = csub(d02, id13);
}

// ---- dual-row radix-4 butterflies (swz8) with LDS twiddle table ----
// wtab[i] = e^{-2*pi*i*j/256}; stage angle -pi*j/(2J) -> index j << (6-lj).
// Max index used anywhere: 3*63 = 189 -> 192-entry table.
__device__ __forceinline__ void fr2_fwd_t(float2* rowA, float2* rowB, int l, int J, int lj,
                                          const float2* wtab) {
  int j = l & (J-1);
  int base = ((l >> lj) << (lj+2)) | j;
  int i0 = swz8(base), i1 = swz8(base+J), i2 = swz8(base+2*J), i3 = swz8(base+3*J);
  int idx = j << (6 - lj);
  float2 a0=rowA[i0], a1=rowA[i1], a2=rowA[i2], a3=rowA[i3];
  float2 b0=rowB[i0], b1=rowB[i1], b2=rowB[i2], b3=rowB[i3];
  float2 w1 = wtab[idx], w2 = wtab[2*idx], w3 = wtab[3*idx];
  {
    float2 t0=cadd(a0,a2), t1=cadd(a1,a3), t2=csub(a0,a2), t3=csub(a1,a3);
    float2 mi=make_float2(t3.y,-t3.x);
    rowA[i0]=cadd(t0,t1);          rowA[i1]=cmul(cadd(t2,mi),w1);
    rowA[i2]=cmul(csub(t0,t1),w2); rowA[i3]=cmul(csub(t2,mi),w3);
  }
  {
    float2 t0=cadd(b0,b2), t1=cadd(b1,b3), t2=csub(b0,b2), t3=csub(b1,b3);
    float2 mi=make_float2(t3.y,-t3.x);
    rowB[i0]=cadd(t0,t1);          rowB[i1]=cmul(cadd(t2,mi),w1);
    rowB[i2]=cmul(csub(t0,t1),w2); rowB[i3]=cmul(csub(t2,mi),w3);
  }
}
__device__ __forceinline__ void fr2_inv_t(float2* rowA, float2* rowB, int l, int J, int lj,
                                          const float2* wtab) {
  int j = l & (J-1);
  int base = ((l >> lj) << (lj+2)) | j;
  int i0 = swz8(base), i1 = swz8(base+J), i2 = swz8(base+2*J), i3 = swz8(base+3*J);
  int idx = j << (6 - lj);
  float2 a0=rowA[i0], a1=rowA[i1], a2=rowA[i2], a3=rowA[i3];
  float2 b0=rowB[i0], b1=rowB[i1], b2=rowB[i2], b3=rowB[i3];
  float2 v1 = cconj(wtab[idx]), v2 = cconj(wtab[2*idx]), v3 = cconj(wtab[3*idx]);
  {
    float2 c1=cmul(a1,v1), c2=cmul(a2,v2), c3=cmul(a3,v3);
    float2 s02=cadd(a0,c2), d02=csub(a0,c2), s13=cadd(c1,c3), d13=csub(c1,c3);
    float2 id13=make_float2(-d13.y,d13.x);
    rowA[i0]=cadd(s02,s13); rowA[i1]=cadd(d02,id13);
    rowA[i2]=csub(s02,s13); rowA[i3]=csub(d02,id13);
  }
  {
    float2 c1=cmul(b1,v1), c2=cmul(b2,v2), c3=cmul(b3,v3);
    float2 s02=cadd(b0,c2), d02=csub(b0,c2), s13=cadd(c1,c3), d13=csub(c1,c3);
    float2 id13=make_float2(-d13.y,d13.x);
    rowB[i0]=cadd(s02,s13); rowB[i1]=cadd(d02,id13);
    rowB[i2]=csub(s02,s13); rowB[i3]=csub(d02,id13);
  }
}

// single-row variants (mono fallback kernel)
__device__ __forceinline__ void fr_stage_fwd(float2* row, int u, int J, int lj) {
  int j = u & (J-1);
  int base = ((u >> lj) << (lj+2)) | j;
  float2 a0 = row[swz8(base)];
  float2 a1 = row[swz8(base+J)];
  float2 a2 = row[swz8(base+2*J)];
  float2 a3 = row[swz8(base+3*J)];
  float sn, cs; __sincosf((float)j * (-PI_F/(2.0f*(float)J)), &sn, &cs);
  float2 w1 = make_float2(cs, sn), w2 = cmul(w1,w1), w3 = cmul(w2,w1);
  float2 t0 = cadd(a0,a2), t1 = cadd(a1,a3), t2 = csub(a0,a2), t3 = csub(a1,a3);
  float2 mi = make_float2(t3.y, -t3.x);
  row[swz8(base)]     = cadd(t0,t1);
  row[swz8(base+J)]   = cmul(cadd(t2,mi), w1);
  row[swz8(base+2*J)] = cmul(csub(t0,t1), w2);
  row[swz8(base+3*J)] = cmul(csub(t2,mi), w3);
}
__device__ __forceinline__ void fr_stage_inv(float2* row, int u, int J, int lj) {
  int j = u & (J-1);
  int base = ((u >> lj) << (lj+2)) | j;
  float sn, cs; __sincosf((float)j * (PI_F/(2.0f*(float)J)), &sn, &cs);
  float2 v1 = make_float2(cs, sn), v2 = cmul(v1,v1), v3 = cmul(v2,v1);
  float2 b0 = row[swz8(base)];
  float2 b1 = cmul(row[swz8(base+J)],   v1);
  float2 b2 = cmul(row[swz8(base+2*J)], v2);
  float2 b3 = cmul(row[swz8(base+3*J)], v3);
  float2 s02 = cadd(b0,b2), d02 = csub(b0,b2), s13 = cadd(b1,b3), d13 = csub(b1,b3);
  float2 id13 = make_float2(-d13.y, d13.x);
  row[swz8(base)]     = cadd(s02, s13);
  row[swz8(base+J)]   = cadd(d02, id13);
  row[swz8(base+2*J)] = csub(s02, s13);
  row[swz8(base+3*J)] = csub(d02, id13);
}

// ---------- aux kernels ----------
__global__ void __launch_bounds__(1024, 1)
atoms_zero(float* __restrict__ out) { out[blockIdx.x * 1024 + threadIdx.x] = 0.0f; }

// ================= SPLIT PATH: kernel A — noise shaping FFT =================
__global__ void __launch_bounds__(1024, 4)
atoms_noise(const float* __restrict__ x, const float* __restrict__ noise,
            float2* __restrict__ nbout) {
  const int blk = blockIdx.x;
  const int t   = threadIdx.x;

  const float* xr = x + (size_t)blk * 533;
  const float* nr = noise + (size_t)blk * 32768;

  __shared__ float2 Cs[16384];   // 128KB
  __shared__ float  ncs[16];

  if (t < 16) ncs[t] = clip01(xr[517 + t]);

  {
    const float4* nr4 = (const float4*)nr;
    #pragma unroll
    for (int i2 = 0; i2 < 8; ++i2) {
      int m = t + (i2 << 10);
      float4 v4 = nr4[m];
      Cs[swz14(2*m)]   = make_float2(v4.x*2.0f-1.0f, v4.y*2.0f-1.0f);
      Cs[swz14(2*m+1)] = make_float2(v4.z*2.0f-1.0f, v4.w*2.0f-1.0f);
    }
  }
  __syncthreads();

  const int ub = ((t >> 6) << 8) + (t & 63);

  #pragma unroll
  for (int r = 0; r < 4; ++r) big_stage_fwd(Cs, ub + (r<<6), 4096, 12);
  __syncthreads();
  #pragma unroll
  for (int r = 0; r < 4; ++r) big_stage_fwd(Cs, ub + (r<<6), 1024, 10);
  __syncthreads();
  #pragma unroll
  for (int r = 0; r < 4; ++r) big_stage_fwd(Cs, ub + (r<<6), 256, 8);
  LGKM();
  #pragma unroll
  for (int r = 0; r < 4; ++r) big_stage_fwd(Cs, ub + (r<<6), 64, 6);
  LGKM();
  #pragma unroll
  for (int r = 0; r < 4; ++r) big_stage_fwd(Cs, ub + (r<<6), 16, 4);
  LGKM();
  #pragma unroll
  for (int r = 0; r < 4; ++r) big_stage_fwd(Cs, ub + (r<<6), 4, 2);
  LGKM();
  #pragma unroll
  for (int r = 0; r < 4; ++r) big_stage_fwd(Cs, ub + (r<<6), 1, 0);
  __syncthreads();

  {
    const float invM = 1.0f / 16384.0f;
    for (int k = t; k < 8192; k += 1024) {
      if (k == 0) {
        float2 Z0 = Cs[0];
        float U0 = Z0.x + Z0.y;
        float UM = Z0.x - Z0.y;
        float V0 = U0 * sshape(0, ncs) * invM;
        float VM = UM * sshape(16384, ncs) * invM;
        Cs[0] = make_float2(0.5f*(V0+VM), 0.5f*(V0-VM));
      } else {
        int pk = swz14(dr14(k));
        int pm = swz14(dr14(16384 - k));
        float2 Zk = Cs[pk], Zm = Cs[pm];
        float sn, cs; __sincosf((float)k * (PI_F / 16384.0f), &sn, &cs);
        float2 Uk, Um; unpack_pair(Zk, Zm, sn, cs, Uk, Um);
        float2 Vk = cscale(Uk, sshape(k, ncs) * invM);
        float2 Vm = cscale(Um, sshape(16384 - k, ncs) * invM);
        float2 Wk, Wm; repack_pair(Vk, Vm, sn, cs, Wk, Wm);
        Cs[pk] = Wk; Cs[pm] = Wm;
      }
    }
    if (t == 0) {  // k = 8192 self-paired bin (dr14(8192)=2)
      int p = swz14(2);
      float2 Z = Cs[p];
      float2 U = make_float2(Z.x, -Z.y);
      float2 V = cscale(U, sshape(8192, ncs) * invM);
      Cs[p] = make_float2(V.x, -V.y);
    }
  }
  __syncthreads();

  #pragma unroll
  for (int r = 0; r < 4; ++r) big_stage_inv(Cs, ub + (r<<6), 1, 0);
  LGKM();
  #pragma unroll
  for (int r = 0; r < 4; ++r) big_stage_inv(Cs, ub + (r<<6), 4, 2);
  LGKM();
  #pragma unroll
  for (int r = 0; r < 4; ++r) big_stage_inv(Cs, ub + (r<<6), 16, 4);
  LGKM();
  #pragma unroll
  for (int r = 0; r < 4; ++r) big_stage_inv(Cs, ub + (r<<6), 64, 6);
  LGKM();
  #pragma unroll
  for (int r = 0; r < 4; ++r) big_stage_inv(Cs, ub + (r<<6), 256, 8);
  __syncthreads();
  #pragma unroll
  for (int r = 0; r < 4; ++r) big_stage_inv(Cs, ub + (r<<6), 1024, 10);
  __syncthreads();
  #pragma unroll
  for (int r = 0; r < 4; ++r) big_stage_inv(Cs, ub + (r<<6), 4096, 12);
  __syncthreads();

  float2* dst = nbout + ((size_t)blk << 14);
  #pragma unroll
  for (int ii = 0; ii < 16; ++ii) {
    int j = t + (ii << 10);
    dst[j] = Cs[swz14(j)];
  }
}

// ================= SPLIT PATH: kernel B — frame loop =================
// r13 structure with LDS cut below 160/3 KB for 3 blocks/CU:
//  - magb+phb -> packed half2 magph (mag lo 16, phase hi 16)
//  - resmag/resphase/msarr -> registers (scan state lives in scan thread)
//  - hamtab -> per-lane registers; wtab 192 entries; utab 128 entries
// LDS: 32768 + 16448 + 2048 + 1536 + 1024 = 53824 B  (<= 54613 = 160KB/3)
// __launch_bounds__(512,2): the only budget this backend compiles spill-free.
__global__ void __launch_bounds__(512, 2)
atoms_frames(const float* __restrict__ x, const float2* __restrict__ nband,
             float2* __restrict__ wsrows) {
  const int blk = blockIdx.x;
  const int t   = threadIdx.x;
  const int w   = t >> 6;            // wave id 0..7
  const int l   = t & 63;

  const float* xr = x + (size_t)blk * 533;
  const float2* nbd = nband + ((size_t)blk << 14);
  float2* wsrow = wsrows + ((size_t)blk << 14);

  __shared__ float2   FR[16][256];      // 32768B
  __shared__ unsigned magph[16*257];    // 16448B packed half (mag, phase)
  __shared__ float2   carrybuf[2][128]; //  2048B
  __shared__ float2   wtab[192];        //  1536B e^{-2 pi i j/256}
  __shared__ float2   utab[128];        //  1024B (cos,sin)(pi k/256)

  // ---- scalar params (block-uniform -> SGPRs) ----
  const float xc0 = clip01(xr[0]);
  const float xc1 = clip01(xr[1]);
  const float amp = clip01(xr[2]);
  const float mean = xc0 * 2.0f - 1.0f;
  const float stdv = xc1 * 0.1f;
  float mu_v = fminf(fmaxf(mean * 32768.0f, -16384.0f), 49152.0f);
  float sigma = fminf(fmaxf((1e-8f + stdv) * 32768.0f, 0.0f), 32767.0f);
  float K_v = -logf(sigma) - 0.91893853320467274f;
  float invsig_v = 1.0f / sigma;
  float istar = fminf(fmaxf(roundf(mu_v), 0.0f), 32767.0f);
  float ds0 = (istar - mu_v) * invsig_v;
  float emax = __expf(-0.5f * ds0 * ds0 + K_v);
  const float mu     = uniformf(mu_v);
  const float invsig = uniformf(invsig_v);
  const float K      = uniformf(K_v);
  const float gscale = uniformf(amp / (emax + 1e-8f));

  if (t < 192) {
    float s, c; __sincosf((float)t * (2.0f*PI_F/256.0f), &s, &c);
    wtab[t] = make_float2(c, -s);
  }
  if (t < 128) {
    float s, c; __sincosf((float)t * (PI_F/256.0f), &s, &c);
    utab[t] = make_float2(c, s);
    carrybuf[0][t] = make_float2(0.0f, 0.0f);
  }
  __syncthreads();

  // ---- per-lane Hamming pairs (positions 2j, 2j+1 for j = l + 64k) ----
  const float W512 = 2.0f * PI_F / 512.0f;
  #define HAMP(n) (0.54f - 0.46f*__cosf((float)(n)*W512))
  const float2 hm0 = make_float2(HAMP(2*l),       HAMP(2*l+1));
  const float2 hm1 = make_float2(HAMP(2*l+128),   HAMP(2*l+129));
  const float2 hm2 = make_float2(HAMP(2*l+256),   HAMP(2*l+257));
  const float2 hm3 = make_float2(HAMP(2*l+384),   HAMP(2*l+385));
  #undef HAMP

  // ---- per-lane resphase registers ----
  #define RPH(k) (clip01(xr[260 + (k)]) * (2.0f*PI_F) - PI_F + (float)(k) * (PI_F/512.0f))
  const float rp1 = RPH(l);          // lane0: bin 0
  const float rp2 = RPH(256 - l);    // lane0: bin 256
  const float rp3 = RPH(l + 64);
  const float rp4 = RPH(192 - l);
  const float rpC = RPH(128);
  // ---- scan state registers (thread t handles bin t, t<257) ----
  float scan_rm = 0.0f, scan_r = 0.0f;
  if (t < 257) scan_rm = 0.01f + 0.99f * clip01(xr[3 + t]);
  #undef RPH

  const float C2 = 0.044194173824159216f;   // 1/sqrt(512)
  const float F2 = 0.08838834764831845f;    // sqrt(512)/256
  const int iA = 2*w, iB = 2*w + 1;
  float2* rowA = FR[iA];
  float2* rowB = FR[iB];

  for (int g = 0; g < 8; ++g) {
    const int fgA = (g << 4) + iA;
    const int fgB = fgA + 1;

    // ---- fused pack + forward stage J=64 (register butterfly, wtab) ----
    #pragma unroll
    for (int s = 0; s < 2; ++s) {
      float2* row = s ? rowB : rowA;
      const int base = (s ? fgB : fgA) << 7;
      float2 a0 = make_float2(0.f,0.f), a1 = a0, a2 = a0, a3 = a0;
      {
        int c0 = base + l;
        if (c0 < 16384) {
          float2 nb = nbd[c0];
          float s0 = (float)(2*c0);
          float d0 = (s0 - mu) * invsig, d1 = (s0 + 1.0f - mu) * invsig;
          a0 = make_float2(__expf(-0.5f*d0*d0 + K)*gscale*nb.x*hm0.x,
                           __expf(-0.5f*d1*d1 + K)*gscale*nb.y*hm0.y);
        }
        int c1 = base + l + 64;
        if (c1 < 16384) {
          float2 nb = nbd[c1];
          float s0 = (float)(2*c1);
          float d0 = (s0 - mu) * invsig, d1 = (s0 + 1.0f - mu) * invsig;
          a1 = make_float2(__expf(-0.5f*d0*d0 + K)*gscale*nb.x*hm1.x,
                           __expf(-0.5f*d1*d1 + K)*gscale*nb.y*hm1.y);
        }
        int c2 = base + l + 128;
        if (c2 < 16384) {
          float2 nb = nbd[c2];
          float s0 = (float)(2*c2);
          float d0 = (s0 - mu) * invsig, d1 = (s0 + 1.0f - mu) * invsig;
          a2 = make_float2(__expf(-0.5f*d0*d0 + K)*gscale*nb.x*hm2.x,
                           __expf(-0.5f*d1*d1 + K)*gscale*nb.y*hm2.y);
        }
        int c3 = base + l + 192;
        if (c3 < 16384) {
          float2 nb = nbd[c3];
          float s0 = (float)(2*c3);
          float d0 = (s0 - mu) * invsig, d1 = (s0 + 1.0f - mu) * invsig;
          a3 = make_float2(__expf(-0.5f*d0*d0 + K)*gscale*nb.x*hm3.x,
                           __expf(-0.5f*d1*d1 + K)*gscale*nb.y*hm3.y);
        }
      }
      float2 w1 = wtab[l], w2 = wtab[2*l], w3 = wtab[3*l];
      float2 t0 = cadd(a0,a2), t1 = cadd(a1,a3), t2 = csub(a0,a2), t3 = csub(a1,a3);
      float2 mi = make_float2(t3.y, -t3.x);
      row[swz8(l)]       = cadd(t0,t1);
      row[swz8(l+64)]    = cmul(cadd(t2,mi), w1);
      row[swz8(l+128)]   = cmul(csub(t0,t1), w2);
      row[swz8(l+192)]   = cmul(csub(t2,mi), w3);
    }
    LGKM();

    // ---- remaining forward stages (LDS, table twiddles) ----
    fr2_fwd_t(rowA, rowB, l, 16, 4, wtab); LGKM();
    fr2_fwd_t(rowA, rowB, l, 4, 2, wtab);  LGKM();
    fr2_fwd_t(rowA, rowB, l, 1, 0, wtab);  LGKM();

    // ---- magnitudes + phases -> packed magph (FR untouched) ----
    if (l == 0) {
      #pragma unroll
      for (int s = 0; s < 2; ++s) {
        float2* row = s ? rowB : rowA;
        int ii = s ? iB : iA;
        float2 Z0 = row[0];
        float U0 = Z0.x + Z0.y, UM = Z0.x - Z0.y;
        magph[ii*257 + 0]   = packmp(fabsf(U0)*C2 + 1e-8f, 0.0f);
        magph[ii*257 + 256] = packmp(fabsf(UM)*C2 + 1e-8f, 0.0f);
        float2 Z = row[swz8(2)];           // self bin k=128 (dr8(128)=2)
        float2 U = make_float2(Z.x, -Z.y);
        float mC = sqrtf(U.x*U.x + U.y*U.y)*C2 + 1e-8f;
        magph[ii*257 + 128] = packmp(mC, (U.y*C2/mC)*PI_F);
      }
    } else {
      int pk = swz8(dr8(l)), pm = swz8(dr8(256 - l));
      float2 uc = utab[l];
      #pragma unroll
      for (int s = 0; s < 2; ++s) {
        float2* row = s ? rowB : rowA;
        int ii = s ? iB : iA;
        float2 Uk, Um; unpack_pair(row[pk], row[pm], uc.y, uc.x, Uk, Um);
        float mk = sqrtf(Uk.x*Uk.x + Uk.y*Uk.y)*C2 + 1e-8f;
        float mm = sqrtf(Um.x*Um.x + Um.y*Um.y)*C2 + 1e-8f;
        magph[ii*257 + l]     = packmp(mk, (Uk.y*C2/mk)*PI_F);
        magph[ii*257 + 256-l] = packmp(mm, (Um.y*C2/mm)*PI_F);
      }
    }
    {
      const int kB = l + 64;
      int pk = swz8(dr8(kB)), pm = swz8(dr8(256 - kB));
      float2 uc = utab[kB];
      #pragma unroll
      for (int s = 0; s < 2; ++s) {
        float2* row = s ? rowB : rowA;
        int ii = s ? iB : iA;
        float2 Uk, Um; unpack_pair(row[pk], row[pm], uc.y, uc.x, Uk, Um);
        float mk = sqrtf(Uk.x*Uk.x + Uk.y*Uk.y)*C2 + 1e-8f;
        float mm = sqrtf(Um.x*Um.x + Um.y*Um.y)*C2 + 1e-8f;
        magph[ii*257 + kB]     = packmp(mk, (Uk.y*C2/mk)*PI_F);
        magph[ii*257 + 256-kB] = packmp(mm, (Um.y*C2/mm)*PI_F);
      }
    }
    __syncthreads();                                   // b1

    // ---- sequential magnitude scan across 16 frames (per bin, reg state) ----
    if (t < 257) {
      unsigned uu[16];
      #pragma unroll
      for (int i = 0; i < 16; ++i) uu[i] = magph[i*257 + t];
      float r = scan_r;
      #pragma unroll
      for (int i = 0; i < 16; ++i) {
        r = fmaf(scan_rm, r, mp_mag(uu[i]));
        magph[i*257 + t] = (uu[i] & 0xFFFF0000u) |
                           (unsigned)__half_as_ushort(__float2half_rn(r));
      }
      scan_r = r;
    }
    __syncthreads();                                   // b2

    // ---- rebuild from scanned mag + stored phase, repack (reg resphase) ----
    {
      const float fmA = (fgA > 0) ? 1.0f : 0.0f;   // fgB >= 1 always -> fm=1
      if (l == 0) {
        #pragma unroll
        for (int s = 0; s < 2; ++s) {
          float2* row = s ? rowB : rowA;
          int ii = s ? iB : iA;
          float fm = s ? 1.0f : fmA;
          float ms0 = mp_mag(magph[ii*257 + 0])   * F2;
          float msM = mp_mag(magph[ii*257 + 256]) * F2;
          float V0 = ms0 * __cosf(fm*rp1);
          float VM = msM * __cosf(fm*rp2);
          row[0] = make_float2(0.5f*(V0+VM), 0.5f*(V0-VM));
          unsigned uC = magph[ii*257 + 128];
          float msC = mp_mag(uC) * F2;
          float pC  = mp_ph(uC) + fm*rpC;
          float sC, cC; __sincosf(pC, &sC, &cC);
          row[swz8(2)] = make_float2(msC*cC, -(msC*sC));
        }
      } else {
        int pk = swz8(dr8(l)), pm = swz8(dr8(256 - l));
        float2 uc = utab[l];
        #pragma unroll
        for (int s = 0; s < 2; ++s) {
          float2* row = s ? rowB : rowA;
          int ii = s ? iB : iA;
          float fm = s ? 1.0f : fmA;
          unsigned uk = magph[ii*257 + l], um = magph[ii*257 + 256-l];
          float msk = mp_mag(uk) * F2;
          float msm = mp_mag(um) * F2;
          float p1 = mp_ph(uk) + fm*rp1;
          float p2 = mp_ph(um) + fm*rp2;
          float s1,c1,s2,c2; __sincosf(p1,&s1,&c1); __sincosf(p2,&s2,&c2);
          float2 Vk = make_float2(msk*c1, msk*s1);
          float2 Vm = make_float2(msm*c2, msm*s2);
          float2 Wk, Wm; repack_pair(Vk, Vm, uc.y, uc.x, Wk, Wm);
          row[pk] = Wk; row[pm] = Wm;
        }
      }
      {
        const int kB = l + 64;
        int pk = swz8(dr8(kB)), pm = swz8(dr8(256 - kB));
        float2 uc = utab[kB];
        #pragma unroll
        for (int s = 0; s < 2; ++s) {
          float2* row = s ? rowB : rowA;
          int ii = s ? iB : iA;
          float fm = s ? 1.0f : fmA;
          unsigned uk = magph[ii*257 + kB], um = magph[ii*257 + 256-kB];
          float msk = mp_mag(uk) * F2;
          float msm = mp_mag(um) * F2;
          float p1 = mp_ph(uk) + fm*rp3;
          float p2 = mp_ph(um) + fm*rp4;
          float s1,c1,s2,c2; __sincosf(p1,&s1,&c1); __sincosf(p2,&s2,&c2);
          float2 Vk = make_float2(msk*c1, msk*s1);
          float2 Vm = make_float2(msm*c2, msm*s2);
          float2 Wk, Wm; repack_pair(Vk, Vm, uc.y, uc.x, Wk, Wm);
          row[pk] = Wk; row[pm] = Wm;
        }
      }
      LGKM();
      fr2_inv_t(rowA, rowB, l, 1, 0, wtab);  LGKM();
      fr2_inv_t(rowA, rowB, l, 4, 2, wtab);  LGKM();
      fr2_inv_t(rowA, rowB, l, 16, 4, wtab); LGKM();
      fr2_inv_t(rowA, rowB, l, 64, 6, wtab);
    }
    __syncthreads();                                   // b3

    // ---- overlap-add emit: 2048 float2 slots / 512 threads ----
    #pragma unroll
    for (int rep = 0; rep < 4; ++rep) {
      int slot = t + (rep << 9);
      int i = slot >> 7, j = slot & 127;
      int fg = (g << 4) + i;
      float2 first  = FR[i][swz8(j)];
      float2 second = (i > 0) ? FR[i-1][swz8(128 + j)] : carrybuf[g & 1][j];
      wsrow[(fg << 7) + j] = cadd(first, second);
      if (i == 15) {  // save carry for next group (double-buffered)
        carrybuf[(g & 1) ^ 1][j] = FR[15][swz8(128 + j)];
      }
    }
    __syncthreads();                                   // b4
  }
}

// ================= MONO fallback (round-5 kernel, proven) =================
__global__ void __launch_bounds__(1024, 4)
atoms_main(const float* __restrict__ x, const float* __restrict__ noise,
           float* __restrict__ outacc, float2* __restrict__ wsbuf, int use_ws) {
  const int blk = blockIdx.x;
  const int b   = blk >> 4;
  const int t   = threadIdx.x;
  const int w   = t >> 6;
  const int l   = t & 63;

  const float* xr = x + (size_t)blk * 533;
  const float* nr = noise + (size_t)blk * 32768;

  __shared__ float2 Cs[16384];
  __shared__ float2 FR[8][256];
  __shared__ float  magb[8*257];
  __shared__ float  resmag[257], resphase[257], msarr[257];
  __shared__ float2 carrybuf[2][128];
  __shared__ float2 hamtab[256];
  __shared__ float  ncs[16];

  const float xc0 = clip01(xr[0]);
  const float xc1 = clip01(xr[1]);
  const float amp = clip01(xr[2]);
  const float mean = xc0 * 2.0f - 1.0f;
  const float stdv = xc1 * 0.1f;
  float mu_v = fminf(fmaxf(mean * 32768.0f, -16384.0f), 49152.0f);
  float sigma = fminf(fmaxf((1e-8f + stdv) * 32768.0f, 0.0f), 32767.0f);
  float K_v = -logf(sigma) - 0.91893853320467274f;
  float invsig_v = 1.0f / sigma;
  float istar = fminf(fmaxf(roundf(mu_v), 0.0f), 32767.0f);
  float ds0 = (istar - mu_v) * invsig_v;
  float emax = __expf(-0.5f * ds0 * ds0 + K_v);
  const float mu     = uniformf(mu_v);
  const float invsig = uniformf(invsig_v);
  const float K      = uniformf(K_v);
  const float gscale = uniformf(amp / (emax + 1e-8f));

  if (t < 257) {
    resmag[t]   = 0.01f + 0.99f * clip01(xr[3 + t]);
    resphase[t] = clip01(xr[260 + t]) * (2.0f*PI_F) - PI_F + (float)t * (PI_F / 512.0f);
    msarr[t]    = 0.0f;
  }
  if (t < 16)  ncs[t] = clip01(xr[517 + t]);
  if (t < 128) carrybuf[0][t] = make_float2(0.0f, 0.0f);
  if (t < 256) {
    const float W512 = 2.0f * PI_F / 512.0f;
    float n0 = (float)(2*t);
    hamtab[t] = make_float2(0.54f - 0.46f*__cosf(n0*W512),
                            0.54f - 0.46f*__cosf((n0+1.0f)*W512));
  }

  {
    const float4* nr4 = (const float4*)nr;
    #pragma unroll
    for (int i2 = 0; i2 < 8; ++i2) {
      int m = t + (i2 << 10);
      float4 v4 = nr4[m];
      Cs[swz14(2*m)]   = make_float2(v4.x*2.0f-1.0f, v4.y*2.0f-1.0f);
      Cs[swz14(2*m+1)] = make_float2(v4.z*2.0f-1.0f, v4.w*2.0f-1.0f);
    }
  }
  __syncthreads();

  const int ub = ((t >> 6) << 8) + (t & 63);

  #pragma unroll
  for (int r = 0; r < 4; ++r) big_stage_fwd(Cs, ub + (r<<6), 4096, 12);
  __syncthreads();
  #pragma unroll
  for (int r = 0; r < 4; ++r) big_stage_fwd(Cs, ub + (r<<6), 1024, 10);
  __syncthreads();
  #pragma unroll
  for (int r = 0; r < 4; ++r) big_stage_fwd(Cs, ub + (r<<6), 256, 8);
  LGKM();
  #pragma unroll
  for (int r = 0; r < 4; ++r) big_stage_fwd(Cs, ub + (r<<6), 64, 6);
  LGKM();
  #pragma unroll
  for (int r = 0; r < 4; ++r) big_stage_fwd(Cs, ub + (r<<6), 16, 4);
  LGKM();
  #pragma unroll
  for (int r = 0; r < 4; ++r) big_stage_fwd(Cs, ub + (r<<6), 4, 2);
  LGKM();
  #pragma unroll
  for (int r = 0; r < 4; ++r) big_stage_fwd(Cs, ub + (r<<6), 1, 0);
  __syncthreads();

  {
    const float invM = 1.0f / 16384.0f;
    for (int k = t; k < 8192; k += 1024) {
      if (k == 0) {
        float2 Z0 = Cs[0];
        float U0 = Z0.x + Z0.y;
        float UM = Z0.x - Z0.y;
        float V0 = U0 * sshape(0, ncs) * invM;
        float VM = UM * sshape(16384, ncs) * invM;
        Cs[0] = make_float2(0.5f*(V0+VM), 0.5f*(V0-VM));
      } else {
        int pk = swz14(dr14(k));
        int pm = swz14(dr14(16384 - k));
        float2 Zk = Cs[pk], Zm = Cs[pm];
        float sn, cs; __sincosf((float)k * (PI_F / 16384.0f), &sn, &cs);
        float2 Uk, Um; unpack_pair(Zk, Zm, sn, cs, Uk, Um);
        float2 Vk = cscale(Uk, sshape(k, ncs) * invM);
        float2 Vm = cscale(Um, sshape(16384 - k, ncs) * invM);
        float2 Wk, Wm; repack_pair(Vk, Vm, sn, cs, Wk, Wm);
        Cs[pk] = Wk; Cs[pm] = Wm;
      }
    }
    if (t == 0) {
      int p = swz14(2);
      float2 Z = Cs[p];
      float2 U = make_float2(Z.x, -Z.y);
      float2 V = cscale(U, sshape(8192, ncs) * (1.0f/16384.0f));
      Cs[p] = make_float2(V.x, -V.y);
    }
  }
  __syncthreads();

  #pragma unroll
  for (int r = 0; r < 4; ++r) big_stage_inv(Cs, ub + (r<<6), 1, 0);
  LGKM();
  #pragma unroll
  for (int r = 0; r < 4; ++r) big_stage_inv(Cs, ub + (r<<6), 4, 2);
  LGKM();
  #pragma unroll
  for (int r = 0; r < 4; ++r) big_stage_inv(Cs, ub + (r<<6), 16, 4);
  LGKM();
  #pragma unroll
  for (int r = 0; r < 4; ++r) big_stage_inv(Cs, ub + (r<<6), 64, 6);
  LGKM();
  #pragma unroll
  for (int r = 0; r < 4; ++r) big_stage_inv(Cs, ub + (r<<6), 256, 8);
  __syncthreads();
  #pragma unroll
  for (int r = 0; r < 4; ++r) big_stage_inv(Cs, ub + (r<<6), 1024, 10);
  __syncthreads();
  #pragma unroll
  for (int r = 0; r < 4; ++r) big_stage_inv(Cs, ub + (r<<6), 4096, 12);
  __syncthreads();

  const float C2 = 0.044194173824159216f;
  const float F2 = 0.08838834764831845f;
  float2* row = (w < 8) ? FR[w] : FR[0];
  float2* wsrow = use_ws ? (wsbuf + ((size_t)blk << 14)) : (float2*)0;

  for (int g = 0; g < 16; ++g) {
    #pragma unroll
    for (int rep = 0; rep < 2; ++rep) {
      int slot = t + (rep << 10);
      int i = slot >> 8, j = slot & 255;
      int fg = (g << 3) + i;
      int cidx = (fg << 7) + j;
      float2 v = make_float2(0.0f, 0.0f);
      if (cidx < 16384) {
        float2 nb = Cs[swz14(cidx)];
        float s0 = (float)(2*cidx);
        float d0 = (s0 - mu) * invsig;
        float d1 = (s0 + 1.0f - mu) * invsig;
        float2 h = hamtab[j];
        v = make_float2(__expf(-0.5f*d0*d0 + K) * gscale * nb.x * h.x,
                        __expf(-0.5f*d1*d1 + K) * gscale * nb.y * h.y);
      }
      FR[i][swz8(j)] = v;
    }
    __syncthreads();

    if (w < 8) {
      fr_stage_fwd(row, l, 64, 6); LGKM();
      fr_stage_fwd(row, l, 16, 4); LGKM();
      fr_stage_fwd(row, l, 4, 2);  LGKM();
      fr_stage_fwd(row, l, 1, 0);  LGKM();

      if (l == 0) {
        float2 Z0 = row[0];
        float U0 = Z0.x + Z0.y, UM = Z0.x - Z0.y;
        magb[w*257 + 0]   = fabsf(U0)*C2 + 1e-8f;
        magb[w*257 + 256] = fabsf(UM)*C2 + 1e-8f;
        float2 Z = row[swz8(2)];
        magb[w*257 + 128] = sqrtf(Z.x*Z.x + Z.y*Z.y)*C2 + 1e-8f;
      } else {
        int pk = swz8(dr8(l)), pm = swz8(dr8(256 - l));
        float sn, cs; __sincosf((float)l * (PI_F/256.0f), &sn, &cs);
        float2 Uk, Um; unpack_pair(row[pk], row[pm], sn, cs, Uk, Um);
        magb[w*257 + l]     = sqrtf(Uk.x*Uk.x + Uk.y*Uk.y)*C2 + 1e-8f;
        magb[w*257 + 256-l] = sqrtf(Um.x*Um.x + Um.y*Um.y)*C2 + 1e-8f;
      }
      {
        const int kB = l + 64;
        int pk = swz8(dr8(kB)), pm = swz8(dr8(256 - kB));
        float sn, cs; __sincosf((float)kB * (PI_F/256.0f), &sn, &cs);
        float2 Uk, Um; unpack_pair(row[pk], row[pm], sn, cs, Uk, Um);
        magb[w*257 + kB]     = sqrtf(Uk.x*Uk.x + Uk.y*Uk.y)*C2 + 1e-8f;
        magb[w*257 + 256-kB] = sqrtf(Um.x*Um.x + Um.y*Um.y)*C2 + 1e-8f;
      }
    }
    __syncthreads();

    if (t < 257) {
      float rm = resmag[t], r = msarr[t];
      #pragma unroll
      for (int i = 0; i < 8; ++i) {
        float mg = magb[i*257 + t];
        r = fmaf(rm, r, mg);
        magb[i*257 + t] = r;
      }
      msarr[t] = r;
    }
    __syncthreads();

    if (w < 8) {
      float fm = ((g << 3) + w > 0) ? 1.0f : 0.0f;
      if (l == 0) {
        float ms0 = magb[w*257 + 0]   * F2;
        float msM = magb[w*257 + 256] * F2;
        float V0 = ms0 * __cosf(fm*resphase[0]);
        float VM = msM * __cosf(fm*resphase[256]);
        row[0] = make_float2(0.5f*(V0+VM), 0.5f*(V0-VM));
        float2 Z = row[swz8(2)];
        float2 U = make_float2(Z.x, -Z.y);
        float mC = sqrtf(U.x*U.x + U.y*U.y)*C2 + 1e-8f;
        float pC = (U.y*C2/mC)*PI_F + fm*resphase[128];
        float msC = magb[w*257 + 128] * F2;
        float sC, cC; __sincosf(pC, &sC, &cC);
        row[swz8(2)] = make_float2(msC*cC, -(msC*sC));
      } else {
        int pk = swz8(dr8(l)), pm = swz8(dr8(256 - l));
        float sn, cs; __sincosf((float)l * (PI_F/256.0f), &sn, &cs);
        float2 Uk, Um; unpack_pair(row[pk], row[pm], sn, cs, Uk, Um);
        float mk = sqrtf(Uk.x*Uk.x + Uk.y*Uk.y)*C2 + 1e-8f;
        float mm = sqrtf(Um.x*Um.x + Um.y*Um.y)*C2 + 1e-8f;
        float p1 = (Uk.y*C2/mk)*PI_F + fm*resphase[l];
        float p2 = (Um.y*C2/mm)*PI_F + fm*resphase[256-l];
        float msk = magb[w*257 + l]     * F2;
        float msm = magb[w*257 + 256-l] * F2;
        float s1,c1,s2,c2; __sincosf(p1,&s1,&c1); __sincosf(p2,&s2,&c2);
        float2 Vk = make_float2(msk*c1, msk*s1);
        float2 Vm = make_float2(msm*c2, msm*s2);
        float2 Wk, Wm; repack_pair(Vk, Vm, sn, cs, Wk, Wm);
        row[pk] = Wk; row[pm] = Wm;
      }
      {
        const int kB = l + 64;
        int pk = swz8(dr8(kB)), pm = swz8(dr8(256 - kB));
        float sn, cs; __sincosf((float)kB * (PI_F/256.0f), &sn, &cs);
        float2 Uk, Um; unpack_pair(row[pk], row[pm], sn, cs, Uk, Um);
        float mk = sqrtf(Uk.x*Uk.x + Uk.y*Uk.y)*C2 + 1e-8f;
        float mm = sqrtf(Um.x*Um.x + Um.y*Um.y)*C2 + 1e-8f;
        float p1 = (Uk.y*C2/mk)*PI_F + fm*resphase[kB];
        float p2 = (Um.y*C2/mm)*PI_F + fm*resphase[256-kB];
        float msk = magb[w*257 + kB]     * F2;
        float msm = magb[w*257 + 256-kB] * F2;
        float s1,c1,s2,c2; __sincosf(p1,&s1,&c1); __sincosf(p2,&s2,&c2);
        float2 Vk = make_float2(msk*c1, msk*s1);
        float2 Vm = make_float2(msm*c2, msm*s2);
        float2 Wk, Wm; repack_pair(Vk, Vm, sn, cs, Wk, Wm);
        row[pk] = Wk; row[pm] = Wm;
      }
      LGKM();
      fr_stage_inv(row, l, 1, 0);  LGKM();
      fr_stage_inv(row, l, 4, 2);  LGKM();
      fr_stage_inv(row, l, 16, 4); LGKM();
      fr_stage_inv(row, l, 64, 6);
    }
    __syncthreads();

    {
      int i = t >> 7, j = t & 127;
      int fg = (g << 3) + i;
      float2 first  = FR[i][swz8(j)];
      float2 second = (i > 0) ? FR[i-1][swz8(128 + j)] : carrybuf[g & 1][j];
      float2 v = cadd(first, second);
      if (use_ws) {
        wsrow[(fg << 7) + j] = v;
      } else {
        float* dst = outacc + (size_t)b*32768 + (fg << 8) + 2*j;
        atomicAdd(dst,     v.x);
        atomicAdd(dst + 1, v.y);
      }
      if (i == 7) {
        carrybuf[(g & 1) ^ 1][j] = FR[7][swz8(128 + j)];
      }
    }
    __syncthreads();
  }
}

// ---------- ws path: sum 16 events + segment max ----------
__global__ void __launch_bounds__(1024, 1)
atoms_sum_max(const float* __restrict__ ws, float* __restrict__ out, float* __restrict__ wmax) {
  int blk = blockIdx.x;               // 256 = 32 b x 8 seg
  int b = blk >> 3, seg = blk & 7, tid = threadIdx.x;
  const float* base = ws + (size_t)b*16*32768 + (size_t)seg*4096;
  float v[4]; float m = 0.0f;
  #pragma unroll
  for (int i = 0; i < 4; ++i) {
    int idx = (i << 10) + tid;
    float s = 0.0f;
    #pragma unroll
    for (int e = 0; e < 16; ++e) s += base[(size_t)e*32768 + idx];
    v[i] = s; m = fmaxf(m, fabsf(s));
  }
  float* op = out + (size_t)b*32768 + (seg << 12);
  #pragma unroll
  for (int i = 0; i < 4; ++i) op[(i<<10) + tid] = v[i];
  __shared__ float red[1024];
  red[tid] = m; __syncthreads();
  for (int s2 = 512; s2 > 0; s2 >>= 1) {
    if (tid < s2) red[tid] = fmaxf(red[tid], red[tid + s2]);
    __syncthreads();
  }
  if (tid == 0) wmax[blk] = red[0];
}

__global__ void __launch_bounds__(1024, 1)
atoms_scale(float* __restrict__ out, const float* __restrict__ wmax) {
  int blk = blockIdx.x;
  int b = blk >> 3, seg = blk & 7, tid = threadIdx.x;
  const float* wm = wmax + b*8;
  float m = fmaxf(fmaxf(fmaxf(wm[0],wm[1]), fmaxf(wm[2],wm[3])),
                  fmaxf(fmaxf(wm[4],wm[5]), fmaxf(wm[6],wm[7])));
  float inv = 1.0f / (m + 1e-8f);
  float* op = out + (size_t)b*32768 + (seg << 12);
  #pragma unroll
  for (int i = 0; i < 4; ++i) op[(i<<10) + tid] *= inv;
}

// ---------- atomic-path fallback norm ----------
__global__ void __launch_bounds__(1024, 1)
atoms_norm(float* __restrict__ out) {
  const int b = blockIdx.x;
  const int tid = threadIdx.x;
  float* p = out + (size_t)b * 32768;
  __shared__ float red[1024];
  float m = 0.0f;
  for (int i = tid; i < 32768; i += 1024) m = fmaxf(m, fabsf(p[i]));
  red[tid] = m;
  __syncthreads();
  for (int s = 512; s > 0; s >>= 1) {
    if (tid < s) red[tid] = fmaxf(red[tid], red[tid + s]);
    __syncthreads();
  }
  const float inv = 1.0f / (red[0] + 1e-8f);
  for (int i = tid; i < 32768; i += 1024) p[i] = p[i] * inv;
}

extern "C" void kernel_launch(void* const* d_in, const int* in_sizes, int n_in,
                              void* d_out, int out_size, void* d_ws, size_t ws_size,
                              hipStream_t stream) {
  (void)in_sizes; (void)n_in; (void)out_size;
  const float* x     = (const float*)d_in[0];
  const float* noise = (const float*)d_in[1];
  float* out = (float*)d_out;

  const size_t rows_f    = 512ull * 32768ull;                 // OLA rows (floats)
  const size_t need_ws    = rows_f*4 + 4096;                  // rows + wmax
  const size_t need_split = rows_f*4 + 4096 + rows_f*4;       // + nband buffer

  if (d_ws != nullptr && ws_size >= need_split) {
    float* ws    = (float*)d_ws;
    float* wmax  = ws + rows_f;
    float2* nbd  = (float2*)(ws + rows_f + 1024);
    atoms_noise <<<512, 1024, 0, stream>>>(x, noise, nbd);
    atoms_frames<<<512,  512, 0, stream>>>(x, nbd, (float2*)ws);
    atoms_sum_max<<<256, 1024, 0, stream>>>(ws, out, wmax);
    atoms_scale<<<256, 1024, 0, stream>>>(out, wmax);
  } else if (d_ws != nullptr && ws_size >= need_ws) {
    float* ws = (float*)d_ws;
    float* wmax = ws + rows_f;
    atoms_main<<<512, 1024, 0, stream>>>(x, noise, nullptr, (float2*)ws, 1);
    atoms_sum_max<<<256, 1024, 0, stream>>>(ws, out, wmax);
    atoms_scale<<<256, 1024, 0, stream>>>(out, wmax);
  } else {
    atoms_zero<<<1024, 1024, 0, stream>>>(out);
    atoms_main<<<512, 1024, 0, stream>>>(x, noise, out, nullptr, 0);
    atoms_norm<<<32, 1024, 0, stream>>>(out);
  }
}

// Round 15
// 229.928 us; speedup vs baseline: 1.0824x; 1.0824x over previous
//
#include <hip/hip_runtime.h>
#include <hip/hip_fp16.h>
#include <math.h>

#define PI_F 3.14159265358979323846f

// ---------- complex helpers ----------
__device__ __forceinline__ float2 cadd(float2 a, float2 b){ return make_float2(a.x+b.x, a.y+b.y); }
__device__ __forceinline__ float2 csub(float2 a, float2 b){ return make_float2(a.x-b.x, a.y-b.y); }
__device__ __forceinline__ float2 cmul(float2 a, float2 b){ return make_float2(a.x*b.x - a.y*b.y, a.x*b.y + a.y*b.x); }
__device__ __forceinline__ float2 cscale(float2 a, float s){ return make_float2(a.x*s, a.y*s); }
__device__ __forceinline__ float clip01(float v){ return fminf(fmaxf(v, 0.0f), 1.0f); }

// force block-uniform float into an SGPR
__device__ __forceinline__ float uniformf(float v){
  return __int_as_float(__builtin_amdgcn_readfirstlane(__float_as_int(v)));
}

// packed half2 <-> float2
__device__ __forceinline__ unsigned pack_h2(float a, float b){
  return ((unsigned)__half_as_ushort(__float2half_rn(b)) << 16) |
          (unsigned)__half_as_ushort(__float2half_rn(a));
}
__device__ __forceinline__ float2 unpack_h2(unsigned u){
  return make_float2(__half2float(__ushort_as_half((unsigned short)(u & 0xFFFFu))),
                     __half2float(__ushort_as_half((unsigned short)(u >> 16))));
}

// LDS bank swizzles
__device__ __forceinline__ int swz14(int p){ return p ^ (15 & ((p>>4) ^ (p>>8) ^ (p>>12))); }
__device__ __forceinline__ int swz8 (int p){ return p ^ ((p>>4) & 15); }

// base-4 digit reversal
__device__ __forceinline__ int dr14(int k){
  unsigned x = __brev((unsigned)k) >> 18;
  return (int)(((x & 0x1555u) << 1) | ((x >> 1) & 0x1555u));
}
__device__ __forceinline__ int dr8(int k){
  unsigned x = __brev((unsigned)k) >> 24;
  return (int)(((x & 0x55u) << 1) | ((x >> 1) & 0x55u));
}

// Real-FFT unpack / repack
__device__ __forceinline__ void unpack_pair(float2 Zk, float2 Zm, float sn, float cs,
                                            float2& Uk, float2& Um) {
  float2 A  = make_float2(0.5f*(Zk.x+Zm.x), 0.5f*(Zk.y-Zm.y));
  float2 B  = make_float2(Zk.x-Zm.x, Zk.y+Zm.y);
  Uk = cadd(A, cmul(B, make_float2(-0.5f*sn, -0.5f*cs)));
  float2 Bm = make_float2(-B.x, B.y);
  Um = cadd(make_float2(A.x, -A.y), cmul(Bm, make_float2(-0.5f*sn, 0.5f*cs)));
}
__device__ __forceinline__ void repack_pair(float2 Vk, float2 Vm, float sn, float cs,
                                            float2& Wk, float2& Wm) {
  float2 P = make_float2(Vk.x+Vm.x, Vk.y-Vm.y);
  float2 Q = make_float2(Vk.x-Vm.x, Vk.y+Vm.y);
  Wk = cscale(cadd(P, cmul(Q, make_float2(-sn, cs))), 0.5f);
  float2 Qm = make_float2(-Q.x, Q.y);
  Wm = cscale(cadd(make_float2(P.x, -P.y), cmul(Qm, make_float2(-sn, -cs))), 0.5f);
}

__device__ __forceinline__ float sshape(int k, const float* ncs) {
  float pos = ((float)k + 0.5f) * (16.0f/16385.0f) - 0.5f;
  pos = fminf(fmaxf(pos, 0.0f), 15.0f);
  float fi = floorf(pos);
  int i0 = (int)fi;
  int i1 = min(i0 + 1, 15);
  float w = pos - fi;
  return ncs[i0]*(1.0f-w) + ncs[i1]*w;
}

#define LGKM() asm volatile("s_waitcnt lgkmcnt(0)" ::: "memory")

// ---- radix-4 butterflies, big buffer (swz14) ----
__device__ __forceinline__ void big_stage_fwd(float2* Cb, int u, int J, int lj) {
  int j = u & (J-1);
  int base = ((u >> lj) << (lj+2)) | j;
  float2 a0 = Cb[swz14(base)];
  float2 a1 = Cb[swz14(base+J)];
  float2 a2 = Cb[swz14(base+2*J)];
  float2 a3 = Cb[swz14(base+3*J)];
  float sn, cs; __sincosf((float)j * (-PI_F/(2.0f*(float)J)), &sn, &cs);
  float2 w1 = make_float2(cs, sn), w2 = cmul(w1,w1), w3 = cmul(w2,w1);
  float2 t0 = cadd(a0,a2), t1 = cadd(a1,a3), t2 = csub(a0,a2), t3 = csub(a1,a3);
  float2 mi = make_float2(t3.y, -t3.x);
  Cb[swz14(base)]     = cadd(t0,t1);
  Cb[swz14(base+J)]   = cmul(cadd(t2,mi), w1);
  Cb[swz14(base+2*J)] = cmul(csub(t0,t1), w2);
  Cb[swz14(base+3*J)] = cmul(csub(t2,mi), w3);
}
__device__ __forceinline__ void big_stage_inv(float2* Cb, int u, int J, int lj) {
  int j = u & (J-1);
  int base = ((u >> lj) << (lj+2)) | j;
  float sn, cs; __sincosf((float)j * (PI_F/(2.0f*(float)J)), &sn, &cs);
  float2 v1 = make_float2(cs, sn), v2 = cmul(v1,v1), v3 = cmul(v2,v1);
  float2 b0 = Cb[swz14(base)];
  float2 b1 = cmul(Cb[swz14(base+J)],   v1);
  float2 b2 = cmul(Cb[swz14(base+2*J)], v2);
  float2 b3 = cmul(Cb[swz14(base+3*J)], v3);
  float2 s02 = cadd(b0,b2), d02 = csub(b0,b2), s13 = cadd(b1,b3), d13 = csub(b1,b3);
  float2 id13 = make_float2(-d13.y, d13.x);
  Cb[swz14(base)]     = cadd(s02, s13);
  Cb[swz14(base+J)]   = cadd(d02, id13);
  Cb[swz14(base+2*J)] = csub(s02, s13);
  Cb[swz14(base+3*J)] = csub(d02, id13);
}

// ---- dual-row radix-4 butterflies (swz8): two frames, one twiddle sincos ----
__device__ __forceinline__ void fr2_fwd(float2* rowA, float2* rowB, int l, int J, int lj) {
  int j = l & (J-1);
  int base = ((l >> lj) << (lj+2)) | j;
  int i0 = swz8(base), i1 = swz8(base+J), i2 = swz8(base+2*J), i3 = swz8(base+3*J);
  float2 a0=rowA[i0], a1=rowA[i1], a2=rowA[i2], a3=rowA[i3];
  float2 b0=rowB[i0], b1=rowB[i1], b2=rowB[i2], b3=rowB[i3];
  float sn, cs; __sincosf((float)j * (-PI_F/(2.0f*(float)J)), &sn, &cs);
  float2 w1 = make_float2(cs, sn), w2 = cmul(w1,w1), w3 = cmul(w2,w1);
  {
    float2 t0=cadd(a0,a2), t1=cadd(a1,a3), t2=csub(a0,a2), t3=csub(a1,a3);
    float2 mi=make_float2(t3.y,-t3.x);
    rowA[i0]=cadd(t0,t1);          rowA[i1]=cmul(cadd(t2,mi),w1);
    rowA[i2]=cmul(csub(t0,t1),w2); rowA[i3]=cmul(csub(t2,mi),w3);
  }
  {
    float2 t0=cadd(b0,b2), t1=cadd(b1,b3), t2=csub(b0,b2), t3=csub(b1,b3);
    float2 mi=make_float2(t3.y,-t3.x);
    rowB[i0]=cadd(t0,t1);          rowB[i1]=cmul(cadd(t2,mi),w1);
    rowB[i2]=cmul(csub(t0,t1),w2); rowB[i3]=cmul(csub(t2,mi),w3);
  }
}
__device__ __forceinline__ void fr2_inv(float2* rowA, float2* rowB, int l, int J, int lj) {
  int j = l & (J-1);
  int base = ((l >> lj) << (lj+2)) | j;
  int i0 = swz8(base), i1 = swz8(base+J), i2 = swz8(base+2*J), i3 = swz8(base+3*J);
  float2 a0=rowA[i0], a1=rowA[i1], a2=rowA[i2], a3=rowA[i3];
  float2 b0=rowB[i0], b1=rowB[i1], b2=rowB[i2], b3=rowB[i3];
  float sn, cs; __sincosf((float)j * (PI_F/(2.0f*(float)J)), &sn, &cs);
  float2 v1 = make_float2(cs, sn), v2 = cmul(v1,v1), v3 = cmul(v2,v1);
  {
    float2 c1=cmul(a1,v1), c2=cmul(a2,v2), c3=cmul(a3,v3);
    float2 s02=cadd(a0,c2), d02=csub(a0,c2), s13=cadd(c1,c3), d13=csub(c1,c3);
    float2 id13=make_float2(-d13.y,d13.x);
    rowA[i0]=cadd(s02,s13); rowA[i1]=cadd(d02,id13);
    rowA[i2]=csub(s02,s13); rowA[i3]=csub(d02,id13);
  }
  {
    float2 c1=cmul(b1,v1), c2=cmul(b2,v2), c3=cmul(b3,v3);
    float2 s02=cadd(b0,c2), d02=csub(b0,c2), s13=cadd(c1,c3), d13=csub(c1,c3);
    float2 id13=make_float2(-d13.y,d13.x);
    rowB[i0]=cadd(s02,s13); rowB[i1]=cadd(d02,id13);
    rowB[i2]=csub(s02,s13); rowB[i3]=csub(d02,id13);
  }
}

// single-row variants (mono fallback kernel)
__device__ __forceinline__ void fr_stage_fwd(float2* row, int u, int J, int lj) {
  int j = u & (J-1);
  int base = ((u >> lj) << (lj+2)) | j;
  float2 a0 = row[swz8(base)];
  float2 a1 = row[swz8(base+J)];
  float2 a2 = row[swz8(base+2*J)];
  float2 a3 = row[swz8(base+3*J)];
  float sn, cs; __sincosf((float)j * (-PI_F/(2.0f*(float)J)), &sn, &cs);
  float2 w1 = make_float2(cs, sn), w2 = cmul(w1,w1), w3 = cmul(w2,w1);
  float2 t0 = cadd(a0,a2), t1 = cadd(a1,a3), t2 = csub(a0,a2), t3 = csub(a1,a3);
  float2 mi = make_float2(t3.y, -t3.x);
  row[swz8(base)]     = cadd(t0,t1);
  row[swz8(base+J)]   = cmul(cadd(t2,mi), w1);
  row[swz8(base+2*J)] = cmul(csub(t0,t1), w2);
  row[swz8(base+3*J)] = cmul(csub(t2,mi), w3);
}
__device__ __forceinline__ void fr_stage_inv(float2* row, int u, int J, int lj) {
  int j = u & (J-1);
  int base = ((u >> lj) << (lj+2)) | j;
  float sn, cs; __sincosf((float)j * (PI_F/(2.0f*(float)J)), &sn, &cs);
  float2 v1 = make_float2(cs, sn), v2 = cmul(v1,v1), v3 = cmul(v2,v1);
  float2 b0 = row[swz8(base)];
  float2 b1 = cmul(row[swz8(base+J)],   v1);
  float2 b2 = cmul(row[swz8(base+2*J)], v2);
  float2 b3 = cmul(row[swz8(base+3*J)], v3);
  float2 s02 = cadd(b0,b2), d02 = csub(b0,b2), s13 = cadd(b1,b3), d13 = csub(b1,b3);
  float2 id13 = make_float2(-d13.y, d13.x);
  row[swz8(base)]     = cadd(s02, s13);
  row[swz8(base+J)]   = cadd(d02, id13);
  row[swz8(base+2*J)] = csub(s02, s13);
  row[swz8(base+3*J)] = csub(d02, id13);
}

// ---------- aux kernels ----------
__global__ void __launch_bounds__(1024, 1)
atoms_zero(float* __restrict__ out) { out[blockIdx.x * 1024 + threadIdx.x] = 0.0f; }

// ================= SPLIT PATH: kernel A — noise shaping FFT (half2 out) ======
__global__ void __launch_bounds__(1024, 4)
atoms_noise(const float* __restrict__ x, const float* __restrict__ noise,
            unsigned* __restrict__ nbout) {
  const int blk = blockIdx.x;
  const int t   = threadIdx.x;

  const float* xr = x + (size_t)blk * 533;
  const float* nr = noise + (size_t)blk * 32768;

  __shared__ float2 Cs[16384];   // 128KB
  __shared__ float  ncs[16];

  if (t < 16) ncs[t] = clip01(xr[517 + t]);

  {
    const float4* nr4 = (const float4*)nr;
    #pragma unroll
    for (int i2 = 0; i2 < 8; ++i2) {
      int m = t + (i2 << 10);
      float4 v4 = nr4[m];
      Cs[swz14(2*m)]   = make_float2(v4.x*2.0f-1.0f, v4.y*2.0f-1.0f);
      Cs[swz14(2*m+1)] = make_float2(v4.z*2.0f-1.0f, v4.w*2.0f-1.0f);
    }
  }
  __syncthreads();

  const int ub = ((t >> 6) << 8) + (t & 63);

  #pragma unroll
  for (int r = 0; r < 4; ++r) big_stage_fwd(Cs, ub + (r<<6), 4096, 12);
  __syncthreads();
  #pragma unroll
  for (int r = 0; r < 4; ++r) big_stage_fwd(Cs, ub + (r<<6), 1024, 10);
  __syncthreads();
  #pragma unroll
  for (int r = 0; r < 4; ++r) big_stage_fwd(Cs, ub + (r<<6), 256, 8);
  LGKM();
  #pragma unroll
  for (int r = 0; r < 4; ++r) big_stage_fwd(Cs, ub + (r<<6), 64, 6);
  LGKM();
  #pragma unroll
  for (int r = 0; r < 4; ++r) big_stage_fwd(Cs, ub + (r<<6), 16, 4);
  LGKM();
  #pragma unroll
  for (int r = 0; r < 4; ++r) big_stage_fwd(Cs, ub + (r<<6), 4, 2);
  LGKM();
  #pragma unroll
  for (int r = 0; r < 4; ++r) big_stage_fwd(Cs, ub + (r<<6), 1, 0);
  __syncthreads();

  {
    const float invM = 1.0f / 16384.0f;
    for (int k = t; k < 8192; k += 1024) {
      if (k == 0) {
        float2 Z0 = Cs[0];
        float U0 = Z0.x + Z0.y;
        float UM = Z0.x - Z0.y;
        float V0 = U0 * sshape(0, ncs) * invM;
        float VM = UM * sshape(16384, ncs) * invM;
        Cs[0] = make_float2(0.5f*(V0+VM), 0.5f*(V0-VM));
      } else {
        int pk = swz14(dr14(k));
        int pm = swz14(dr14(16384 - k));
        float2 Zk = Cs[pk], Zm = Cs[pm];
        float sn, cs; __sincosf((float)k * (PI_F / 16384.0f), &sn, &cs);
        float2 Uk, Um; unpack_pair(Zk, Zm, sn, cs, Uk, Um);
        float2 Vk = cscale(Uk, sshape(k, ncs) * invM);
        float2 Vm = cscale(Um, sshape(16384 - k, ncs) * invM);
        float2 Wk, Wm; repack_pair(Vk, Vm, sn, cs, Wk, Wm);
        Cs[pk] = Wk; Cs[pm] = Wm;
      }
    }
    if (t == 0) {  // k = 8192 self-paired bin (dr14(8192)=2)
      int p = swz14(2);
      float2 Z = Cs[p];
      float2 U = make_float2(Z.x, -Z.y);
      float2 V = cscale(U, sshape(8192, ncs) * invM);
      Cs[p] = make_float2(V.x, -V.y);
    }
  }
  __syncthreads();

  #pragma unroll
  for (int r = 0; r < 4; ++r) big_stage_inv(Cs, ub + (r<<6), 1, 0);
  LGKM();
  #pragma unroll
  for (int r = 0; r < 4; ++r) big_stage_inv(Cs, ub + (r<<6), 4, 2);
  LGKM();
  #pragma unroll
  for (int r = 0; r < 4; ++r) big_stage_inv(Cs, ub + (r<<6), 16, 4);
  LGKM();
  #pragma unroll
  for (int r = 0; r < 4; ++r) big_stage_inv(Cs, ub + (r<<6), 64, 6);
  LGKM();
  #pragma unroll
  for (int r = 0; r < 4; ++r) big_stage_inv(Cs, ub + (r<<6), 256, 8);
  __syncthreads();
  #pragma unroll
  for (int r = 0; r < 4; ++r) big_stage_inv(Cs, ub + (r<<6), 1024, 10);
  __syncthreads();
  #pragma unroll
  for (int r = 0; r < 4; ++r) big_stage_inv(Cs, ub + (r<<6), 4096, 12);
  __syncthreads();

  unsigned* dst = nbout + ((size_t)blk << 14);
  #pragma unroll
  for (int ii = 0; ii < 16; ++ii) {
    int j = t + (ii << 10);
    float2 v = Cs[swz14(j)];
    dst[j] = pack_h2(v.x, v.y);
  }
}

// ================= SPLIT PATH: kernel B — frame loop (r11 base, half2 I/O) ===
// __launch_bounds__(512,2): the only budget this backend compiles spill-free.
__global__ void __launch_bounds__(512, 2)
atoms_frames(const float* __restrict__ x, const unsigned* __restrict__ nband,
             unsigned* __restrict__ wsrows) {
  const int blk = blockIdx.x;
  const int t   = threadIdx.x;
  const int w   = t >> 6;            // wave id 0..7
  const int l   = t & 63;

  const float* xr = x + (size_t)blk * 533;
  const unsigned* nbd = nband + ((size_t)blk << 14);
  unsigned* wsrow = wsrows + ((size_t)blk << 14);

  __shared__ float2 FR[16][256];        // 32KB
  __shared__ float  magb[16*257];       // 16.4KB
  __shared__ float  phb[16*257];        // 16.4KB
  __shared__ float  resmag[257], resphase[257], msarr[257];
  __shared__ float2 carrybuf[2][128];
  __shared__ float2 hamtab[256];

  // ---- scalar params (block-uniform -> SGPRs) ----
  const float xc0 = clip01(xr[0]);
  const float xc1 = clip01(xr[1]);
  const float amp = clip01(xr[2]);
  const float mean = xc0 * 2.0f - 1.0f;
  const float stdv = xc1 * 0.1f;
  float mu_v = fminf(fmaxf(mean * 32768.0f, -16384.0f), 49152.0f);
  float sigma = fminf(fmaxf((1e-8f + stdv) * 32768.0f, 0.0f), 32767.0f);
  float K_v = -logf(sigma) - 0.91893853320467274f;
  float invsig_v = 1.0f / sigma;
  float istar = fminf(fmaxf(roundf(mu_v), 0.0f), 32767.0f);
  float ds0 = (istar - mu_v) * invsig_v;
  float emax = __expf(-0.5f * ds0 * ds0 + K_v);
  const float mu     = uniformf(mu_v);
  const float invsig = uniformf(invsig_v);
  const float K      = uniformf(K_v);
  const float gscale = uniformf(amp / (emax + 1e-8f));

  if (t < 257) {
    resmag[t]   = 0.01f + 0.99f * clip01(xr[3 + t]);
    resphase[t] = clip01(xr[260 + t]) * (2.0f*PI_F) - PI_F + (float)t * (PI_F / 512.0f);
    msarr[t]    = 0.0f;
  }
  if (t < 128) carrybuf[0][t] = make_float2(0.0f, 0.0f);
  if (t < 256) {
    const float W512 = 2.0f * PI_F / 512.0f;
    float n0 = (float)(2*t);
    hamtab[t] = make_float2(0.54f - 0.46f*__cosf(n0*W512),
                            0.54f - 0.46f*__cosf((n0+1.0f)*W512));
  }
  __syncthreads();

  // Hamming window pairs this lane will ever touch (fixed across groups/rows)
  const float2 hm0 = hamtab[l];
  const float2 hm1 = hamtab[l + 64];
  const float2 hm2 = hamtab[l + 128];
  const float2 hm3 = hamtab[l + 192];

  const float C2 = 0.044194173824159216f;   // 1/sqrt(512)
  const float F2 = 0.08838834764831845f;    // sqrt(512)/256
  const int iA = 2*w, iB = 2*w + 1;
  float2* rowA = FR[iA];
  float2* rowB = FR[iB];

  for (int g = 0; g < 8; ++g) {
    const int fgA = (g << 4) + iA;
    const int fgB = fgA + 1;

    // ---- (a) fused pack + forward stage J=64 (register butterfly) ----
    #pragma unroll
    for (int s = 0; s < 2; ++s) {
      float2* row = s ? rowB : rowA;
      const int base = (s ? fgB : fgA) << 7;
      float2 a0 = make_float2(0.f,0.f), a1 = a0, a2 = a0, a3 = a0;
      {
        int c0 = base + l;
        if (c0 < 16384) {
          float2 nb = unpack_h2(nbd[c0]);
          float s0 = (float)(2*c0);
          float d0 = (s0 - mu) * invsig, d1 = (s0 + 1.0f - mu) * invsig;
          a0 = make_float2(__expf(-0.5f*d0*d0 + K)*gscale*nb.x*hm0.x,
                           __expf(-0.5f*d1*d1 + K)*gscale*nb.y*hm0.y);
        }
        int c1 = base + l + 64;
        if (c1 < 16384) {
          float2 nb = unpack_h2(nbd[c1]);
          float s0 = (float)(2*c1);
          float d0 = (s0 - mu) * invsig, d1 = (s0 + 1.0f - mu) * invsig;
          a1 = make_float2(__expf(-0.5f*d0*d0 + K)*gscale*nb.x*hm1.x,
                           __expf(-0.5f*d1*d1 + K)*gscale*nb.y*hm1.y);
        }
        int c2 = base + l + 128;
        if (c2 < 16384) {
          float2 nb = unpack_h2(nbd[c2]);
          float s0 = (float)(2*c2);
          float d0 = (s0 - mu) * invsig, d1 = (s0 + 1.0f - mu) * invsig;
          a2 = make_float2(__expf(-0.5f*d0*d0 + K)*gscale*nb.x*hm2.x,
                           __expf(-0.5f*d1*d1 + K)*gscale*nb.y*hm2.y);
        }
        int c3 = base + l + 192;
        if (c3 < 16384) {
          float2 nb = unpack_h2(nbd[c3]);
          float s0 = (float)(2*c3);
          float d0 = (s0 - mu) * invsig, d1 = (s0 + 1.0f - mu) * invsig;
          a3 = make_float2(__expf(-0.5f*d0*d0 + K)*gscale*nb.x*hm3.x,
                           __expf(-0.5f*d1*d1 + K)*gscale*nb.y*hm3.y);
        }
      }
      float sn, cs; __sincosf((float)l * (-PI_F/128.0f), &sn, &cs);
      float2 w1 = make_float2(cs, sn), w2 = cmul(w1,w1), w3 = cmul(w2,w1);
      float2 t0 = cadd(a0,a2), t1 = cadd(a1,a3), t2 = csub(a0,a2), t3 = csub(a1,a3);
      float2 mi = make_float2(t3.y, -t3.x);
      row[swz8(l)]       = cadd(t0,t1);
      row[swz8(l+64)]    = cmul(cadd(t2,mi), w1);
      row[swz8(l+128)]   = cmul(csub(t0,t1), w2);
      row[swz8(l+192)]   = cmul(csub(t2,mi), w3);
    }
    LGKM();

    // ---- remaining forward stages (LDS) ----
    fr2_fwd(rowA, rowB, l, 16, 4); LGKM();
    fr2_fwd(rowA, rowB, l, 4, 2);  LGKM();
    fr2_fwd(rowA, rowB, l, 1, 0);  LGKM();

    // ---- magnitudes + phases -> magb/phb (FR untouched) ----
    if (l == 0) {
      #pragma unroll
      for (int s = 0; s < 2; ++s) {
        float2* row = s ? rowB : rowA;
        int ii = s ? iB : iA;
        float2 Z0 = row[0];
        float U0 = Z0.x + Z0.y, UM = Z0.x - Z0.y;
        magb[ii*257 + 0]   = fabsf(U0)*C2 + 1e-8f;
        magb[ii*257 + 256] = fabsf(UM)*C2 + 1e-8f;
        float2 Z = row[swz8(2)];           // self bin k=128 (dr8(128)=2)
        float2 U = make_float2(Z.x, -Z.y);
        float mC = sqrtf(U.x*U.x + U.y*U.y)*C2 + 1e-8f;
        magb[ii*257 + 128] = mC;
        phb[ii*257 + 128]  = (U.y*C2/mC)*PI_F;
      }
    } else {
      int pk = swz8(dr8(l)), pm = swz8(dr8(256 - l));
      float sn, cs; __sincosf((float)l * (PI_F/256.0f), &sn, &cs);
      #pragma unroll
      for (int s = 0; s < 2; ++s) {
        float2* row = s ? rowB : rowA;
        int ii = s ? iB : iA;
        float2 Uk, Um; unpack_pair(row[pk], row[pm], sn, cs, Uk, Um);
        float mk = sqrtf(Uk.x*Uk.x + Uk.y*Uk.y)*C2 + 1e-8f;
        float mm = sqrtf(Um.x*Um.x + Um.y*Um.y)*C2 + 1e-8f;
        magb[ii*257 + l]     = mk;
        magb[ii*257 + 256-l] = mm;
        phb[ii*257 + l]      = (Uk.y*C2/mk)*PI_F;
        phb[ii*257 + 256-l]  = (Um.y*C2/mm)*PI_F;
      }
    }
    {
      const int kB = l + 64;
      int pk = swz8(dr8(kB)), pm = swz8(dr8(256 - kB));
      float sn, cs; __sincosf((float)kB * (PI_F/256.0f), &sn, &cs);
      #pragma unroll
      for (int s = 0; s < 2; ++s) {
        float2* row = s ? rowB : rowA;
        int ii = s ? iB : iA;
        float2 Uk, Um; unpack_pair(row[pk], row[pm], sn, cs, Uk, Um);
        float mk = sqrtf(Uk.x*Uk.x + Uk.y*Uk.y)*C2 + 1e-8f;
        float mm = sqrtf(Um.x*Um.x + Um.y*Um.y)*C2 + 1e-8f;
        magb[ii*257 + kB]     = mk;
        magb[ii*257 + 256-kB] = mm;
        phb[ii*257 + kB]      = (Uk.y*C2/mk)*PI_F;
        phb[ii*257 + 256-kB]  = (Um.y*C2/mm)*PI_F;
      }
    }
    __syncthreads();

    // ---- sequential magnitude scan across the 16 frames (per bin) ----
    if (t < 257) {
      float rm = resmag[t], r = msarr[t];
      float mg[16];
      #pragma unroll
      for (int i = 0; i < 16; ++i) mg[i] = magb[i*257 + t];
      #pragma unroll
      for (int i = 0; i < 16; ++i) {
        r = fmaf(rm, r, mg[i]);
        magb[i*257 + t] = r;
      }
      msarr[t] = r;
    }
    __syncthreads();

    // ---- rebuild from scanned mag + stored phase, repack ----
    {
      const float fmA = (fgA > 0) ? 1.0f : 0.0f;   // fgB >= 1 always -> fm=1
      if (l == 0) {
        #pragma unroll
        for (int s = 0; s < 2; ++s) {
          float2* row = s ? rowB : rowA;
          int ii = s ? iB : iA;
          float fm = s ? 1.0f : fmA;
          float ms0 = magb[ii*257 + 0]   * F2;
          float msM = magb[ii*257 + 256] * F2;
          float V0 = ms0 * __cosf(fm*resphase[0]);
          float VM = msM * __cosf(fm*resphase[256]);
          row[0] = make_float2(0.5f*(V0+VM), 0.5f*(V0-VM));
          float msC = magb[ii*257 + 128] * F2;
          float pC  = phb[ii*257 + 128] + fm*resphase[128];
          float sC, cC; __sincosf(pC, &sC, &cC);
          row[swz8(2)] = make_float2(msC*cC, -(msC*sC));
        }
      } else {
        int pk = swz8(dr8(l)), pm = swz8(dr8(256 - l));
        float sn, cs; __sincosf((float)l * (PI_F/256.0f), &sn, &cs);
        float rp1 = resphase[l], rp2 = resphase[256-l];
        #pragma unroll
        for (int s = 0; s < 2; ++s) {
          float2* row = s ? rowB : rowA;
          int ii = s ? iB : iA;
          float fm = s ? 1.0f : fmA;
          float msk = magb[ii*257 + l]     * F2;
          float msm = magb[ii*257 + 256-l] * F2;
          float p1 = phb[ii*257 + l]     + fm*rp1;
          float p2 = phb[ii*257 + 256-l] + fm*rp2;
          float s1,c1,s2,c2; __sincosf(p1,&s1,&c1); __sincosf(p2,&s2,&c2);
          float2 Vk = make_float2(msk*c1, msk*s1);
          float2 Vm = make_float2(msm*c2, msm*s2);
          float2 Wk, Wm; repack_pair(Vk, Vm, sn, cs, Wk, Wm);
          row[pk] = Wk; row[pm] = Wm;
        }
      }
      {
        const int kB = l + 64;
        int pk = swz8(dr8(kB)), pm = swz8(dr8(256 - kB));
        float sn, cs; __sincosf((float)kB * (PI_F/256.0f), &sn, &cs);
        float rp1 = resphase[kB], rp2 = resphase[256-kB];
        #pragma unroll
        for (int s = 0; s < 2; ++s) {
          float2* row = s ? rowB : rowA;
          int ii = s ? iB : iA;
          float fm = s ? 1.0f : fmA;
          float msk = magb[ii*257 + kB]     * F2;
          float msm = magb[ii*257 + 256-kB] * F2;
          float p1 = phb[ii*257 + kB]     + fm*rp1;
          float p2 = phb[ii*257 + 256-kB] + fm*rp2;
          float s1,c1,s2,c2; __sincosf(p1,&s1,&c1); __sincosf(p2,&s2,&c2);
          float2 Vk = make_float2(msk*c1, msk*s1);
          float2 Vm = make_float2(msm*c2, msm*s2);
          float2 Wk, Wm; repack_pair(Vk, Vm, sn, cs, Wk, Wm);
          row[pk] = Wk; row[pm] = Wm;
        }
      }
      LGKM();
      fr2_inv(rowA, rowB, l, 1, 0);  LGKM();
      fr2_inv(rowA, rowB, l, 4, 2);  LGKM();
      fr2_inv(rowA, rowB, l, 16, 4); LGKM();
      fr2_inv(rowA, rowB, l, 64, 6);
    }
    __syncthreads();

    // ---- overlap-add emit: 2048 pair slots / 512 threads = 4 reps ----
    #pragma unroll
    for (int rep = 0; rep < 4; ++rep) {
      int slot = t + (rep << 9);
      int i = slot >> 7, j = slot & 127;
      int fg = (g << 4) + i;
      float2 first  = FR[i][swz8(j)];
      float2 second = (i > 0) ? FR[i-1][swz8(128 + j)] : carrybuf[g & 1][j];
      float2 v = cadd(first, second);
      wsrow[(fg << 7) + j] = pack_h2(v.x, v.y);
      if (i == 15) {  // save carry for next group (double-buffered)
        carrybuf[(g & 1) ^ 1][j] = FR[15][swz8(128 + j)];
      }
    }
    __syncthreads();
  }
}

// ================= MONO fallback (round-5 kernel, proven, f32) ===============
__global__ void __launch_bounds__(1024, 4)
atoms_main(const float* __restrict__ x, const float* __restrict__ noise,
           float* __restrict__ outacc, float2* __restrict__ wsbuf, int use_ws) {
  const int blk = blockIdx.x;
  const int b   = blk >> 4;
  const int t   = threadIdx.x;
  const int w   = t >> 6;
  const int l   = t & 63;

  const float* xr = x + (size_t)blk * 533;
  const float* nr = noise + (size_t)blk * 32768;

  __shared__ float2 Cs[16384];
  __shared__ float2 FR[8][256];
  __shared__ float  magb[8*257];
  __shared__ float  resmag[257], resphase[257], msarr[257];
  __shared__ float2 carrybuf[2][128];
  __shared__ float2 hamtab[256];
  __shared__ float  ncs[16];

  const float xc0 = clip01(xr[0]);
  const float xc1 = clip01(xr[1]);
  const float amp = clip01(xr[2]);
  const float mean = xc0 * 2.0f - 1.0f;
  const float stdv = xc1 * 0.1f;
  float mu_v = fminf(fmaxf(mean * 32768.0f, -16384.0f), 49152.0f);
  float sigma = fminf(fmaxf((1e-8f + stdv) * 32768.0f, 0.0f), 32767.0f);
  float K_v = -logf(sigma) - 0.91893853320467274f;
  float invsig_v = 1.0f / sigma;
  float istar = fminf(fmaxf(roundf(mu_v), 0.0f), 32767.0f);
  float ds0 = (istar - mu_v) * invsig_v;
  float emax = __expf(-0.5f * ds0 * ds0 + K_v);
  const float mu     = uniformf(mu_v);
  const float invsig = uniformf(invsig_v);
  const float K      = uniformf(K_v);
  const float gscale = uniformf(amp / (emax + 1e-8f));

  if (t < 257) {
    resmag[t]   = 0.01f + 0.99f * clip01(xr[3 + t]);
    resphase[t] = clip01(xr[260 + t]) * (2.0f*PI_F) - PI_F + (float)t * (PI_F / 512.0f);
    msarr[t]    = 0.0f;
  }
  if (t < 16)  ncs[t] = clip01(xr[517 + t]);
  if (t < 128) carrybuf[0][t] = make_float2(0.0f, 0.0f);
  if (t < 256) {
    const float W512 = 2.0f * PI_F / 512.0f;
    float n0 = (float)(2*t);
    hamtab[t] = make_float2(0.54f - 0.46f*__cosf(n0*W512),
                            0.54f - 0.46f*__cosf((n0+1.0f)*W512));
  }

  {
    const float4* nr4 = (const float4*)nr;
    #pragma unroll
    for (int i2 = 0; i2 < 8; ++i2) {
      int m = t + (i2 << 10);
      float4 v4 = nr4[m];
      Cs[swz14(2*m)]   = make_float2(v4.x*2.0f-1.0f, v4.y*2.0f-1.0f);
      Cs[swz14(2*m+1)] = make_float2(v4.z*2.0f-1.0f, v4.w*2.0f-1.0f);
    }
  }
  __syncthreads();

  const int ub = ((t >> 6) << 8) + (t & 63);

  #pragma unroll
  for (int r = 0; r < 4; ++r) big_stage_fwd(Cs, ub + (r<<6), 4096, 12);
  __syncthreads();
  #pragma unroll
  for (int r = 0; r < 4; ++r) big_stage_fwd(Cs, ub + (r<<6), 1024, 10);
  __syncthreads();
  #pragma unroll
  for (int r = 0; r < 4; ++r) big_stage_fwd(Cs, ub + (r<<6), 256, 8);
  LGKM();
  #pragma unroll
  for (int r = 0; r < 4; ++r) big_stage_fwd(Cs, ub + (r<<6), 64, 6);
  LGKM();
  #pragma unroll
  for (int r = 0; r < 4; ++r) big_stage_fwd(Cs, ub + (r<<6), 16, 4);
  LGKM();
  #pragma unroll
  for (int r = 0; r < 4; ++r) big_stage_fwd(Cs, ub + (r<<6), 4, 2);
  LGKM();
  #pragma unroll
  for (int r = 0; r < 4; ++r) big_stage_fwd(Cs, ub + (r<<6), 1, 0);
  __syncthreads();

  {
    const float invM = 1.0f / 16384.0f;
    for (int k = t; k < 8192; k += 1024) {
      if (k == 0) {
        float2 Z0 = Cs[0];
        float U0 = Z0.x + Z0.y;
        float UM = Z0.x - Z0.y;
        float V0 = U0 * sshape(0, ncs) * invM;
        float VM = UM * sshape(16384, ncs) * invM;
        Cs[0] = make_float2(0.5f*(V0+VM), 0.5f*(V0-VM));
      } else {
        int pk = swz14(dr14(k));
        int pm = swz14(dr14(16384 - k));
        float2 Zk = Cs[pk], Zm = Cs[pm];
        float sn, cs; __sincosf((float)k * (PI_F / 16384.0f), &sn, &cs);
        float2 Uk, Um; unpack_pair(Zk, Zm, sn, cs, Uk, Um);
        float2 Vk = cscale(Uk, sshape(k, ncs) * invM);
        float2 Vm = cscale(Um, sshape(16384 - k, ncs) * invM);
        float2 Wk, Wm; repack_pair(Vk, Vm, sn, cs, Wk, Wm);
        Cs[pk] = Wk; Cs[pm] = Wm;
      }
    }
    if (t == 0) {
      int p = swz14(2);
      float2 Z = Cs[p];
      float2 U = make_float2(Z.x, -Z.y);
      float2 V = cscale(U, sshape(8192, ncs) * (1.0f/16384.0f));
      Cs[p] = make_float2(V.x, -V.y);
    }
  }
  __syncthreads();

  #pragma unroll
  for (int r = 0; r < 4; ++r) big_stage_inv(Cs, ub + (r<<6), 1, 0);
  LGKM();
  #pragma unroll
  for (int r = 0; r < 4; ++r) big_stage_inv(Cs, ub + (r<<6), 4, 2);
  LGKM();
  #pragma unroll
  for (int r = 0; r < 4; ++r) big_stage_inv(Cs, ub + (r<<6), 16, 4);
  LGKM();
  #pragma unroll
  for (int r = 0; r < 4; ++r) big_stage_inv(Cs, ub + (r<<6), 64, 6);
  LGKM();
  #pragma unroll
  for (int r = 0; r < 4; ++r) big_stage_inv(Cs, ub + (r<<6), 256, 8);
  __syncthreads();
  #pragma unroll
  for (int r = 0; r < 4; ++r) big_stage_inv(Cs, ub + (r<<6), 1024, 10);
  __syncthreads();
  #pragma unroll
  for (int r = 0; r < 4; ++r) big_stage_inv(Cs, ub + (r<<6), 4096, 12);
  __syncthreads();

  const float C2 = 0.044194173824159216f;
  const float F2 = 0.08838834764831845f;
  float2* row = (w < 8) ? FR[w] : FR[0];
  float2* wsrow = use_ws ? (wsbuf + ((size_t)blk << 14)) : (float2*)0;

  for (int g = 0; g < 16; ++g) {
    #pragma unroll
    for (int rep = 0; rep < 2; ++rep) {
      int slot = t + (rep << 10);
      int i = slot >> 8, j = slot & 255;
      int fg = (g << 3) + i;
      int cidx = (fg << 7) + j;
      float2 v = make_float2(0.0f, 0.0f);
      if (cidx < 16384) {
        float2 nb = Cs[swz14(cidx)];
        float s0 = (float)(2*cidx);
        float d0 = (s0 - mu) * invsig;
        float d1 = (s0 + 1.0f - mu) * invsig;
        float2 h = hamtab[j];
        v = make_float2(__expf(-0.5f*d0*d0 + K) * gscale * nb.x * h.x,
                        __expf(-0.5f*d1*d1 + K) * gscale * nb.y * h.y);
      }
      FR[i][swz8(j)] = v;
    }
    __syncthreads();

    if (w < 8) {
      fr_stage_fwd(row, l, 64, 6); LGKM();
      fr_stage_fwd(row, l, 16, 4); LGKM();
      fr_stage_fwd(row, l, 4, 2);  LGKM();
      fr_stage_fwd(row, l, 1, 0);  LGKM();

      if (l == 0) {
        float2 Z0 = row[0];
        float U0 = Z0.x + Z0.y, UM = Z0.x - Z0.y;
        magb[w*257 + 0]   = fabsf(U0)*C2 + 1e-8f;
        magb[w*257 + 256] = fabsf(UM)*C2 + 1e-8f;
        float2 Z = row[swz8(2)];
        magb[w*257 + 128] = sqrtf(Z.x*Z.x + Z.y*Z.y)*C2 + 1e-8f;
      } else {
        int pk = swz8(dr8(l)), pm = swz8(dr8(256 - l));
        float sn, cs; __sincosf((float)l * (PI_F/256.0f), &sn, &cs);
        float2 Uk, Um; unpack_pair(row[pk], row[pm], sn, cs, Uk, Um);
        magb[w*257 + l]     = sqrtf(Uk.x*Uk.x + Uk.y*Uk.y)*C2 + 1e-8f;
        magb[w*257 + 256-l] = sqrtf(Um.x*Um.x + Um.y*Um.y)*C2 + 1e-8f;
      }
      {
        const int kB = l + 64;
        int pk = swz8(dr8(kB)), pm = swz8(dr8(256 - kB));
        float sn, cs; __sincosf((float)kB * (PI_F/256.0f), &sn, &cs);
        float2 Uk, Um; unpack_pair(row[pk], row[pm], sn, cs, Uk, Um);
        magb[w*257 + kB]     = sqrtf(Uk.x*Uk.x + Uk.y*Uk.y)*C2 + 1e-8f;
        magb[w*257 + 256-kB] = sqrtf(Um.x*Um.x + Um.y*Um.y)*C2 + 1e-8f;
      }
    }
    __syncthreads();

    if (t < 257) {
      float rm = resmag[t], r = msarr[t];
      #pragma unroll
      for (int i = 0; i < 8; ++i) {
        float mg = magb[i*257 + t];
        r = fmaf(rm, r, mg);
        magb[i*257 + t] = r;
      }
      msarr[t] = r;
    }
    __syncthreads();

    if (w < 8) {
      float fm = ((g << 3) + w > 0) ? 1.0f : 0.0f;
      if (l == 0) {
        float ms0 = magb[w*257 + 0]   * F2;
        float msM = magb[w*257 + 256] * F2;
        float V0 = ms0 * __cosf(fm*resphase[0]);
        float VM = msM * __cosf(fm*resphase[256]);
        row[0] = make_float2(0.5f*(V0+VM), 0.5f*(V0-VM));
        float2 Z = row[swz8(2)];
        float2 U = make_float2(Z.x, -Z.y);
        float mC = sqrtf(U.x*U.x + U.y*U.y)*C2 + 1e-8f;
        float pC = (U.y*C2/mC)*PI_F + fm*resphase[128];
        float msC = magb[w*257 + 128] * F2;
        float sC, cC; __sincosf(pC, &sC, &cC);
        row[swz8(2)] = make_float2(msC*cC, -(msC*sC));
      } else {
        int pk = swz8(dr8(l)), pm = swz8(dr8(256 - l));
        float sn, cs; __sincosf((float)l * (PI_F/256.0f), &sn, &cs);
        float2 Uk, Um; unpack_pair(row[pk], row[pm], sn, cs, Uk, Um);
        float mk = sqrtf(Uk.x*Uk.x + Uk.y*Uk.y)*C2 + 1e-8f;
        float mm = sqrtf(Um.x*Um.x + Um.y*Um.y)*C2 + 1e-8f;
        float p1 = (Uk.y*C2/mk)*PI_F + fm*resphase[l];
        float p2 = (Um.y*C2/mm)*PI_F + fm*resphase[256-l];
        float msk = magb[w*257 + l]     * F2;
        float msm = magb[w*257 + 256-l] * F2;
        float s1,c1,s2,c2; __sincosf(p1,&s1,&c1); __sincosf(p2,&s2,&c2);
        float2 Vk = make_float2(msk*c1, msk*s1);
        float2 Vm = make_float2(msm*c2, msm*s2);
        float2 Wk, Wm; repack_pair(Vk, Vm, sn, cs, Wk, Wm);
        row[pk] = Wk; row[pm] = Wm;
      }
      {
        const int kB = l + 64;
        int pk = swz8(dr8(kB)), pm = swz8(dr8(256 - kB));
        float sn, cs; __sincosf((float)kB * (PI_F/256.0f), &sn, &cs);
        float2 Uk, Um; unpack_pair(row[pk], row[pm], sn, cs, Uk, Um);
        float mk = sqrtf(Uk.x*Uk.x + Uk.y*Uk.y)*C2 + 1e-8f;
        float mm = sqrtf(Um.x*Um.x + Um.y*Um.y)*C2 + 1e-8f;
        float p1 = (Uk.y*C2/mk)*PI_F + fm*resphase[kB];
        float p2 = (Um.y*C2/mm)*PI_F + fm*resphase[256-kB];
        float msk = magb[w*257 + kB]     * F2;
        float msm = magb[w*257 + 256-kB] * F2;
        float s1,c1,s2,c2; __sincosf(p1,&s1,&c1); __sincosf(p2,&s2,&c2);
        float2 Vk = make_float2(msk*c1, msk*s1);
        float2 Vm = make_float2(msm*c2, msm*s2);
        float2 Wk, Wm; repack_pair(Vk, Vm, sn, cs, Wk, Wm);
        row[pk] = Wk; row[pm] = Wm;
      }
      LGKM();
      fr_stage_inv(row, l, 1, 0);  LGKM();
      fr_stage_inv(row, l, 4, 2);  LGKM();
      fr_stage_inv(row, l, 16, 4); LGKM();
      fr_stage_inv(row, l, 64, 6);
    }
    __syncthreads();

    {
      int i = t >> 7, j = t & 127;
      int fg = (g << 3) + i;
      float2 first  = FR[i][swz8(j)];
      float2 second = (i > 0) ? FR[i-1][swz8(128 + j)] : carrybuf[g & 1][j];
      float2 v = cadd(first, second);
      if (use_ws) {
        wsrow[(fg << 7) + j] = v;
      } else {
        float* dst = outacc + (size_t)b*32768 + (fg << 8) + 2*j;
        atomicAdd(dst,     v.x);
        atomicAdd(dst + 1, v.y);
      }
      if (i == 7) {
        carrybuf[(g & 1) ^ 1][j] = FR[7][swz8(128 + j)];
      }
    }
    __syncthreads();
  }
}

// ---------- ws path: sum 16 events + segment max (half rows) ----------
__global__ void __launch_bounds__(1024, 1)
atoms_sum_max_h(const unsigned* __restrict__ ws, float* __restrict__ out, float* __restrict__ wmax) {
  int blk = blockIdx.x;               // 256 = 32 b x 8 seg
  int b = blk >> 3, seg = blk & 7, tid = threadIdx.x;
  const unsigned* base = ws + (size_t)b*16*16384 + (size_t)seg*2048;
  float2 v[2]; float m = 0.0f;
  #pragma unroll
  for (int i = 0; i < 2; ++i) {
    int idx = tid + (i << 10);
    float2 s = make_float2(0.0f, 0.0f);
    #pragma unroll
    for (int e = 0; e < 16; ++e) {
      float2 u = unpack_h2(base[(size_t)e*16384 + idx]);
      s.x += u.x; s.y += u.y;
    }
    v[i] = s;
    m = fmaxf(m, fmaxf(fabsf(s.x), fabsf(s.y)));
  }
  float2* op = (float2*)(out + (size_t)b*32768 + (seg << 12));
  #pragma unroll
  for (int i = 0; i < 2; ++i) op[tid + (i << 10)] = v[i];
  __shared__ float red[1024];
  red[tid] = m; __syncthreads();
  for (int s2 = 512; s2 > 0; s2 >>= 1) {
    if (tid < s2) red[tid] = fmaxf(red[tid], red[tid + s2]);
    __syncthreads();
  }
  if (tid == 0) wmax[blk] = red[0];
}

// ---------- ws path: sum 16 events + segment max (f32 rows, fallback) --------
__global__ void __launch_bounds__(1024, 1)
atoms_sum_max(const float* __restrict__ ws, float* __restrict__ out, float* __restrict__ wmax) {
  int blk = blockIdx.x;               // 256 = 32 b x 8 seg
  int b = blk >> 3, seg = blk & 7, tid = threadIdx.x;
  const float* base = ws + (size_t)b*16*32768 + (size_t)seg*4096;
  float v[4]; float m = 0.0f;
  #pragma unroll
  for (int i = 0; i < 4; ++i) {
    int idx = (i << 10) + tid;
    float s = 0.0f;
    #pragma unroll
    for (int e = 0; e < 16; ++e) s += base[(size_t)e*32768 + idx];
    v[i] = s; m = fmaxf(m, fabsf(s));
  }
  float* op = out + (size_t)b*32768 + (seg << 12);
  #pragma unroll
  for (int i = 0; i < 4; ++i) op[(i<<10) + tid] = v[i];
  __shared__ float red[1024];
  red[tid] = m; __syncthreads();
  for (int s2 = 512; s2 > 0; s2 >>= 1) {
    if (tid < s2) red[tid] = fmaxf(red[tid], red[tid + s2]);
    __syncthreads();
  }
  if (tid == 0) wmax[blk] = red[0];
}

__global__ void __launch_bounds__(1024, 1)
atoms_scale(float* __restrict__ out, const float* __restrict__ wmax) {
  int blk = blockIdx.x;
  int b = blk >> 3, seg = blk & 7, tid = threadIdx.x;
  const float* wm = wmax + b*8;
  float m = fmaxf(fmaxf(fmaxf(wm[0],wm[1]), fmaxf(wm[2],wm[3])),
                  fmaxf(fmaxf(wm[4],wm[5]), fmaxf(wm[6],wm[7])));
  float inv = 1.0f / (m + 1e-8f);
  float* op = out + (size_t)b*32768 + (seg << 12);
  #pragma unroll
  for (int i = 0; i < 4; ++i) op[(i<<10) + tid] *= inv;
}

// ---------- atomic-path fallback norm ----------
__global__ void __launch_bounds__(1024, 1)
atoms_norm(float* __restrict__ out) {
  const int b = blockIdx.x;
  const int tid = threadIdx.x;
  float* p = out + (size_t)b * 32768;
  __shared__ float red[1024];
  float m = 0.0f;
  for (int i = tid; i < 32768; i += 1024) m = fmaxf(m, fabsf(p[i]));
  red[tid] = m;
  __syncthreads();
  for (int s = 512; s > 0; s >>= 1) {
    if (tid < s) red[tid] = fmaxf(red[tid], red[tid + s]);
    __syncthreads();
  }
  const float inv = 1.0f / (red[0] + 1e-8f);
  for (int i = tid; i < 32768; i += 1024) p[i] = p[i] * inv;
}

extern "C" void kernel_launch(void* const* d_in, const int* in_sizes, int n_in,
                              void* d_out, int out_size, void* d_ws, size_t ws_size,
                              hipStream_t stream) {
  (void)in_sizes; (void)n_in; (void)out_size;
  const float* x     = (const float*)d_in[0];
  const float* noise = (const float*)d_in[1];
  float* out = (float*)d_out;

  const size_t pairs_u    = 512ull * 16384ull;                // pairs per buffer (u32 each)
  const size_t rows_f     = 512ull * 32768ull;                // f32 rows (fallback)
  const size_t need_ws    = rows_f*4 + 4096;                  // f32 rows + wmax (fallback)
  const size_t need_split = pairs_u*4 + 4096 + pairs_u*4;     // half rows + wmax + half nband

  if (d_ws != nullptr && ws_size >= need_split) {
    unsigned* ws_u = (unsigned*)d_ws;
    float*    wmax = (float*)(ws_u + pairs_u);
    unsigned* nbd  = ws_u + pairs_u + 1024;
    atoms_noise <<<512, 1024, 0, stream>>>(x, noise, nbd);
    atoms_frames<<<512,  512, 0, stream>>>(x, nbd, ws_u);
    atoms_sum_max_h<<<256, 1024, 0, stream>>>(ws_u, out, wmax);
    atoms_scale<<<256, 1024, 0, stream>>>(out, wmax);
  } else if (d_ws != nullptr && ws_size >= need_ws) {
    float* ws = (float*)d_ws;
    float* wmax = ws + rows_f;
    atoms_main<<<512, 1024, 0, stream>>>(x, noise, nullptr, (float2*)ws, 1);
    atoms_sum_max<<<256, 1024, 0, stream>>>(ws, out, wmax);
    atoms_scale<<<256, 1024, 0, stream>>>(out, wmax);
  } else {
    atoms_zero<<<1024, 1024, 0, stream>>>(out);
    atoms_main<<<512, 1024, 0, stream>>>(x, noise, out, nullptr, 0);
    atoms_norm<<<32, 1024, 0, stream>>>(out);
  }
}

// Round 16
// 228.077 us; speedup vs baseline: 1.0912x; 1.0081x over previous
//
#include <hip/hip_runtime.h>
#include <hip/hip_fp16.h>
#include <math.h>

#define PI_F 3.14159265358979323846f

// ---------- complex helpers ----------
__device__ __forceinline__ float2 cadd(float2 a, float2 b){ return make_float2(a.x+b.x, a.y+b.y); }
__device__ __forceinline__ float2 csub(float2 a, float2 b){ return make_float2(a.x-b.x, a.y-b.y); }
__device__ __forceinline__ float2 cmul(float2 a, float2 b){ return make_float2(a.x*b.x - a.y*b.y, a.x*b.y + a.y*b.x); }
__device__ __forceinline__ float2 cscale(float2 a, float s){ return make_float2(a.x*s, a.y*s); }
__device__ __forceinline__ float clip01(float v){ return fminf(fmaxf(v, 0.0f), 1.0f); }

// force block-uniform float into an SGPR
__device__ __forceinline__ float uniformf(float v){
  return __int_as_float(__builtin_amdgcn_readfirstlane(__float_as_int(v)));
}

// packed half2 <-> float2
__device__ __forceinline__ unsigned pack_h2(float a, float b){
  return ((unsigned)__half_as_ushort(__float2half_rn(b)) << 16) |
          (unsigned)__half_as_ushort(__float2half_rn(a));
}
__device__ __forceinline__ float2 unpack_h2(unsigned u){
  return make_float2(__half2float(__ushort_as_half((unsigned short)(u & 0xFFFFu))),
                     __half2float(__ushort_as_half((unsigned short)(u >> 16))));
}

// LDS bank swizzles
__device__ __forceinline__ int swz14(int p){ return p ^ (15 & ((p>>4) ^ (p>>8) ^ (p>>12))); }
__device__ __forceinline__ int swz8 (int p){ return p ^ ((p>>4) & 15); }

// base-4 digit reversal
__device__ __forceinline__ int dr14(int k){
  unsigned x = __brev((unsigned)k) >> 18;
  return (int)(((x & 0x1555u) << 1) | ((x >> 1) & 0x1555u));
}
__device__ __forceinline__ int dr8(int k){
  unsigned x = __brev((unsigned)k) >> 24;
  return (int)(((x & 0x55u) << 1) | ((x >> 1) & 0x55u));
}

// Real-FFT unpack / repack
__device__ __forceinline__ void unpack_pair(float2 Zk, float2 Zm, float sn, float cs,
                                            float2& Uk, float2& Um) {
  float2 A  = make_float2(0.5f*(Zk.x+Zm.x), 0.5f*(Zk.y-Zm.y));
  float2 B  = make_float2(Zk.x-Zm.x, Zk.y+Zm.y);
  Uk = cadd(A, cmul(B, make_float2(-0.5f*sn, -0.5f*cs)));
  float2 Bm = make_float2(-B.x, B.y);
  Um = cadd(make_float2(A.x, -A.y), cmul(Bm, make_float2(-0.5f*sn, 0.5f*cs)));
}
__device__ __forceinline__ void repack_pair(float2 Vk, float2 Vm, float sn, float cs,
                                            float2& Wk, float2& Wm) {
  float2 P = make_float2(Vk.x+Vm.x, Vk.y-Vm.y);
  float2 Q = make_float2(Vk.x-Vm.x, Vk.y+Vm.y);
  Wk = cscale(cadd(P, cmul(Q, make_float2(-sn, cs))), 0.5f);
  float2 Qm = make_float2(-Q.x, Q.y);
  Wm = cscale(cadd(make_float2(P.x, -P.y), cmul(Qm, make_float2(-sn, -cs))), 0.5f);
}

__device__ __forceinline__ float sshape(int k, const float* ncs) {
  float pos = ((float)k + 0.5f) * (16.0f/16385.0f) - 0.5f;
  pos = fminf(fmaxf(pos, 0.0f), 15.0f);
  float fi = floorf(pos);
  int i0 = (int)fi;
  int i1 = min(i0 + 1, 15);
  float w = pos - fi;
  return ncs[i0]*(1.0f-w) + ncs[i1]*w;
}

#define LGKM() asm volatile("s_waitcnt lgkmcnt(0)" ::: "memory")

// ---- radix-4 butterflies, big buffer (swz14), f32 LDS (mono fallback) ----
__device__ __forceinline__ void big_stage_fwd(float2* Cb, int u, int J, int lj) {
  int j = u & (J-1);
  int base = ((u >> lj) << (lj+2)) | j;
  float2 a0 = Cb[swz14(base)];
  float2 a1 = Cb[swz14(base+J)];
  float2 a2 = Cb[swz14(base+2*J)];
  float2 a3 = Cb[swz14(base+3*J)];
  float sn, cs; __sincosf((float)j * (-PI_F/(2.0f*(float)J)), &sn, &cs);
  float2 w1 = make_float2(cs, sn), w2 = cmul(w1,w1), w3 = cmul(w2,w1);
  float2 t0 = cadd(a0,a2), t1 = cadd(a1,a3), t2 = csub(a0,a2), t3 = csub(a1,a3);
  float2 mi = make_float2(t3.y, -t3.x);
  Cb[swz14(base)]     = cadd(t0,t1);
  Cb[swz14(base+J)]   = cmul(cadd(t2,mi), w1);
  Cb[swz14(base+2*J)] = cmul(csub(t0,t1), w2);
  Cb[swz14(base+3*J)] = cmul(csub(t2,mi), w3);
}
__device__ __forceinline__ void big_stage_inv(float2* Cb, int u, int J, int lj) {
  int j = u & (J-1);
  int base = ((u >> lj) << (lj+2)) | j;
  float sn, cs; __sincosf((float)j * (PI_F/(2.0f*(float)J)), &sn, &cs);
  float2 v1 = make_float2(cs, sn), v2 = cmul(v1,v1), v3 = cmul(v2,v1);
  float2 b0 = Cb[swz14(base)];
  float2 b1 = cmul(Cb[swz14(base+J)],   v1);
  float2 b2 = cmul(Cb[swz14(base+2*J)], v2);
  float2 b3 = cmul(Cb[swz14(base+3*J)], v3);
  float2 s02 = cadd(b0,b2), d02 = csub(b0,b2), s13 = cadd(b1,b3), d13 = csub(b1,b3);
  float2 id13 = make_float2(-d13.y, d13.x);
  Cb[swz14(base)]     = cadd(s02, s13);
  Cb[swz14(base+J)]   = cadd(d02, id13);
  Cb[swz14(base+2*J)] = csub(s02, s13);
  Cb[swz14(base+3*J)] = csub(d02, id13);
}

// ---- radix-4 butterflies, big buffer, packed-half LDS (noise kernel) ----
__device__ __forceinline__ void big_stage_fwd_h(unsigned* Cb, int u, int J, int lj) {
  int j = u & (J-1);
  int base = ((u >> lj) << (lj+2)) | j;
  float2 a0 = unpack_h2(Cb[swz14(base)]);
  float2 a1 = unpack_h2(Cb[swz14(base+J)]);
  float2 a2 = unpack_h2(Cb[swz14(base+2*J)]);
  float2 a3 = unpack_h2(Cb[swz14(base+3*J)]);
  float sn, cs; __sincosf((float)j * (-PI_F/(2.0f*(float)J)), &sn, &cs);
  float2 w1 = make_float2(cs, sn), w2 = cmul(w1,w1), w3 = cmul(w2,w1);
  float2 t0 = cadd(a0,a2), t1 = cadd(a1,a3), t2 = csub(a0,a2), t3 = csub(a1,a3);
  float2 mi = make_float2(t3.y, -t3.x);
  float2 r0 = cadd(t0,t1);
  float2 r1 = cmul(cadd(t2,mi), w1);
  float2 r2 = cmul(csub(t0,t1), w2);
  float2 r3 = cmul(csub(t2,mi), w3);
  Cb[swz14(base)]     = pack_h2(r0.x, r0.y);
  Cb[swz14(base+J)]   = pack_h2(r1.x, r1.y);
  Cb[swz14(base+2*J)] = pack_h2(r2.x, r2.y);
  Cb[swz14(base+3*J)] = pack_h2(r3.x, r3.y);
}
__device__ __forceinline__ void big_stage_inv_h(unsigned* Cb, int u, int J, int lj) {
  int j = u & (J-1);
  int base = ((u >> lj) << (lj+2)) | j;
  float sn, cs; __sincosf((float)j * (PI_F/(2.0f*(float)J)), &sn, &cs);
  float2 v1 = make_float2(cs, sn), v2 = cmul(v1,v1), v3 = cmul(v2,v1);
  float2 b0 = unpack_h2(Cb[swz14(base)]);
  float2 b1 = cmul(unpack_h2(Cb[swz14(base+J)]),   v1);
  float2 b2 = cmul(unpack_h2(Cb[swz14(base+2*J)]), v2);
  float2 b3 = cmul(unpack_h2(Cb[swz14(base+3*J)]), v3);
  float2 s02 = cadd(b0,b2), d02 = csub(b0,b2), s13 = cadd(b1,b3), d13 = csub(b1,b3);
  float2 id13 = make_float2(-d13.y, d13.x);
  float2 r0 = cadd(s02, s13);
  float2 r1 = cadd(d02, id13);
  float2 r2 = csub(s02, s13);
  float2 r3 = csub(d02, id13);
  Cb[swz14(base)]     = pack_h2(r0.x, r0.y);
  Cb[swz14(base+J)]   = pack_h2(r1.x, r1.y);
  Cb[swz14(base+2*J)] = pack_h2(r2.x, r2.y);
  Cb[swz14(base+3*J)] = pack_h2(r3.x, r3.y);
}

// ---- dual-row radix-4 butterflies (swz8): two frames, one twiddle sincos ----
__device__ __forceinline__ void fr2_fwd(float2* rowA, float2* rowB, int l, int J, int lj) {
  int j = l & (J-1);
  int base = ((l >> lj) << (lj+2)) | j;
  int i0 = swz8(base), i1 = swz8(base+J), i2 = swz8(base+2*J), i3 = swz8(base+3*J);
  float2 a0=rowA[i0], a1=rowA[i1], a2=rowA[i2], a3=rowA[i3];
  float2 b0=rowB[i0], b1=rowB[i1], b2=rowB[i2], b3=rowB[i3];
  float sn, cs; __sincosf((float)j * (-PI_F/(2.0f*(float)J)), &sn, &cs);
  float2 w1 = make_float2(cs, sn), w2 = cmul(w1,w1), w3 = cmul(w2,w1);
  {
    float2 t0=cadd(a0,a2), t1=cadd(a1,a3), t2=csub(a0,a2), t3=csub(a1,a3);
    float2 mi=make_float2(t3.y,-t3.x);
    rowA[i0]=cadd(t0,t1);          rowA[i1]=cmul(cadd(t2,mi),w1);
    rowA[i2]=cmul(csub(t0,t1),w2); rowA[i3]=cmul(csub(t2,mi),w3);
  }
  {
    float2 t0=cadd(b0,b2), t1=cadd(b1,b3), t2=csub(b0,b2), t3=csub(b1,b3);
    float2 mi=make_float2(t3.y,-t3.x);
    rowB[i0]=cadd(t0,t1);          rowB[i1]=cmul(cadd(t2,mi),w1);
    rowB[i2]=cmul(csub(t0,t1),w2); rowB[i3]=cmul(csub(t2,mi),w3);
  }
}
__device__ __forceinline__ void fr2_inv(float2* rowA, float2* rowB, int l, int J, int lj) {
  int j = l & (J-1);
  int base = ((l >> lj) << (lj+2)) | j;
  int i0 = swz8(base), i1 = swz8(base+J), i2 = swz8(base+2*J), i3 = swz8(base+3*J);
  float2 a0=rowA[i0], a1=rowA[i1], a2=rowA[i2], a3=rowA[i3];
  float2 b0=rowB[i0], b1=rowB[i1], b2=rowB[i2], b3=rowB[i3];
  float sn, cs; __sincosf((float)j * (PI_F/(2.0f*(float)J)), &sn, &cs);
  float2 v1 = make_float2(cs, sn), v2 = cmul(v1,v1), v3 = cmul(v2,v1);
  {
    float2 c1=cmul(a1,v1), c2=cmul(a2,v2), c3=cmul(a3,v3);
    float2 s02=cadd(a0,c2), d02=csub(a0,c2), s13=cadd(c1,c3), d13=csub(c1,c3);
    float2 id13=make_float2(-d13.y,d13.x);
    rowA[i0]=cadd(s02,s13); rowA[i1]=cadd(d02,id13);
    rowA[i2]=csub(s02,s13); rowA[i3]=csub(d02,id13);
  }
  {
    float2 c1=cmul(b1,v1), c2=cmul(b2,v2), c3=cmul(b3,v3);
    float2 s02=cadd(b0,c2), d02=csub(b0,c2), s13=cadd(c1,c3), d13=csub(c1,c3);
    float2 id13=make_float2(-d13.y,d13.x);
    rowB[i0]=cadd(s02,s13); rowB[i1]=cadd(d02,id13);
    rowB[i2]=csub(s02,s13); rowB[i3]=csub(d02,id13);
  }
}

// single-row variants (mono fallback kernel)
__device__ __forceinline__ void fr_stage_fwd(float2* row, int u, int J, int lj) {
  int j = u & (J-1);
  int base = ((u >> lj) << (lj+2)) | j;
  float2 a0 = row[swz8(base)];
  float2 a1 = row[swz8(base+J)];
  float2 a2 = row[swz8(base+2*J)];
  float2 a3 = row[swz8(base+3*J)];
  float sn, cs; __sincosf((float)j * (-PI_F/(2.0f*(float)J)), &sn, &cs);
  float2 w1 = make_float2(cs, sn), w2 = cmul(w1,w1), w3 = cmul(w2,w1);
  float2 t0 = cadd(a0,a2), t1 = cadd(a1,a3), t2 = csub(a0,a2), t3 = csub(a1,a3);
  float2 mi = make_float2(t3.y, -t3.x);
  row[swz8(base)]     = cadd(t0,t1);
  row[swz8(base+J)]   = cmul(cadd(t2,mi), w1);
  row[swz8(base+2*J)] = cmul(csub(t0,t1), w2);
  row[swz8(base+3*J)] = cmul(csub(t2,mi), w3);
}
__device__ __forceinline__ void fr_stage_inv(float2* row, int u, int J, int lj) {
  int j = u & (J-1);
  int base = ((u >> lj) << (lj+2)) | j;
  float sn, cs; __sincosf((float)j * (PI_F/(2.0f*(float)J)), &sn, &cs);
  float2 v1 = make_float2(cs, sn), v2 = cmul(v1,v1), v3 = cmul(v2,v1);
  float2 b0 = row[swz8(base)];
  float2 b1 = cmul(row[swz8(base+J)],   v1);
  float2 b2 = cmul(row[swz8(base+2*J)], v2);
  float2 b3 = cmul(row[swz8(base+3*J)], v3);
  float2 s02 = cadd(b0,b2), d02 = csub(b0,b2), s13 = cadd(b1,b3), d13 = csub(b1,b3);
  float2 id13 = make_float2(-d13.y, d13.x);
  row[swz8(base)]     = cadd(s02, s13);
  row[swz8(base+J)]   = cadd(d02, id13);
  row[swz8(base+2*J)] = csub(s02, s13);
  row[swz8(base+3*J)] = csub(d02, id13);
}

// ---------- aux kernels ----------
__global__ void __launch_bounds__(1024, 1)
atoms_zero(float* __restrict__ out) { out[blockIdx.x * 1024 + threadIdx.x] = 0.0f; }

// ================= SPLIT PATH: kernel A — noise shaping FFT =================
// Packed-half LDS buffer (64KB) -> 2 blocks/CU so barrier/LGKM latency in one
// block hides behind the other. Butterfly math stays f32; only LDS storage is
// half. Output already packed (free final conversion).
__global__ void __launch_bounds__(1024, 2)
atoms_noise(const float* __restrict__ x, const float* __restrict__ noise,
            unsigned* __restrict__ nbout) {
  const int blk = blockIdx.x;
  const int t   = threadIdx.x;

  const float* xr = x + (size_t)blk * 533;
  const float* nr = noise + (size_t)blk * 32768;

  __shared__ unsigned Csh[16384];   // 64KB packed half2
  __shared__ float  ncs[16];

  if (t < 16) ncs[t] = clip01(xr[517 + t]);

  {
    const float4* nr4 = (const float4*)nr;
    #pragma unroll
    for (int i2 = 0; i2 < 8; ++i2) {
      int m = t + (i2 << 10);
      float4 v4 = nr4[m];
      Csh[swz14(2*m)]   = pack_h2(v4.x*2.0f-1.0f, v4.y*2.0f-1.0f);
      Csh[swz14(2*m+1)] = pack_h2(v4.z*2.0f-1.0f, v4.w*2.0f-1.0f);
    }
  }
  __syncthreads();

  const int ub = ((t >> 6) << 8) + (t & 63);

  #pragma unroll
  for (int r = 0; r < 4; ++r) big_stage_fwd_h(Csh, ub + (r<<6), 4096, 12);
  __syncthreads();
  #pragma unroll
  for (int r = 0; r < 4; ++r) big_stage_fwd_h(Csh, ub + (r<<6), 1024, 10);
  __syncthreads();
  #pragma unroll
  for (int r = 0; r < 4; ++r) big_stage_fwd_h(Csh, ub + (r<<6), 256, 8);
  LGKM();
  #pragma unroll
  for (int r = 0; r < 4; ++r) big_stage_fwd_h(Csh, ub + (r<<6), 64, 6);
  LGKM();
  #pragma unroll
  for (int r = 0; r < 4; ++r) big_stage_fwd_h(Csh, ub + (r<<6), 16, 4);
  LGKM();
  #pragma unroll
  for (int r = 0; r < 4; ++r) big_stage_fwd_h(Csh, ub + (r<<6), 4, 2);
  LGKM();
  #pragma unroll
  for (int r = 0; r < 4; ++r) big_stage_fwd_h(Csh, ub + (r<<6), 1, 0);
  __syncthreads();

  {
    const float invM = 1.0f / 16384.0f;
    for (int k = t; k < 8192; k += 1024) {
      if (k == 0) {
        float2 Z0 = unpack_h2(Csh[0]);
        float U0 = Z0.x + Z0.y;
        float UM = Z0.x - Z0.y;
        float V0 = U0 * sshape(0, ncs) * invM;
        float VM = UM * sshape(16384, ncs) * invM;
        Csh[0] = pack_h2(0.5f*(V0+VM), 0.5f*(V0-VM));
      } else {
        int pk = swz14(dr14(k));
        int pm = swz14(dr14(16384 - k));
        float2 Zk = unpack_h2(Csh[pk]), Zm = unpack_h2(Csh[pm]);
        float sn, cs; __sincosf((float)k * (PI_F / 16384.0f), &sn, &cs);
        float2 Uk, Um; unpack_pair(Zk, Zm, sn, cs, Uk, Um);
        float2 Vk = cscale(Uk, sshape(k, ncs) * invM);
        float2 Vm = cscale(Um, sshape(16384 - k, ncs) * invM);
        float2 Wk, Wm; repack_pair(Vk, Vm, sn, cs, Wk, Wm);
        Csh[pk] = pack_h2(Wk.x, Wk.y);
        Csh[pm] = pack_h2(Wm.x, Wm.y);
      }
    }
    if (t == 0) {  // k = 8192 self-paired bin (dr14(8192)=2)
      int p = swz14(2);
      float2 Z = unpack_h2(Csh[p]);
      float2 U = make_float2(Z.x, -Z.y);
      float2 V = cscale(U, sshape(8192, ncs) * invM);
      Csh[p] = pack_h2(V.x, -V.y);
    }
  }
  __syncthreads();

  #pragma unroll
  for (int r = 0; r < 4; ++r) big_stage_inv_h(Csh, ub + (r<<6), 1, 0);
  LGKM();
  #pragma unroll
  for (int r = 0; r < 4; ++r) big_stage_inv_h(Csh, ub + (r<<6), 4, 2);
  LGKM();
  #pragma unroll
  for (int r = 0; r < 4; ++r) big_stage_inv_h(Csh, ub + (r<<6), 16, 4);
  LGKM();
  #pragma unroll
  for (int r = 0; r < 4; ++r) big_stage_inv_h(Csh, ub + (r<<6), 64, 6);
  LGKM();
  #pragma unroll
  for (int r = 0; r < 4; ++r) big_stage_inv_h(Csh, ub + (r<<6), 256, 8);
  __syncthreads();
  #pragma unroll
  for (int r = 0; r < 4; ++r) big_stage_inv_h(Csh, ub + (r<<6), 1024, 10);
  __syncthreads();
  #pragma unroll
  for (int r = 0; r < 4; ++r) big_stage_inv_h(Csh, ub + (r<<6), 4096, 12);
  __syncthreads();

  unsigned* dst = nbout + ((size_t)blk << 14);
  #pragma unroll
  for (int ii = 0; ii < 16; ++ii) {
    int j = t + (ii << 10);
    dst[j] = Csh[swz14(j)];           // already packed half2
  }
}

// ================= SPLIT PATH: kernel B — frame loop (r11 base, half2 I/O) ===
// __launch_bounds__(512,2): the only budget this backend compiles spill-free.
__global__ void __launch_bounds__(512, 2)
atoms_frames(const float* __restrict__ x, const unsigned* __restrict__ nband,
             unsigned* __restrict__ wsrows) {
  const int blk = blockIdx.x;
  const int t   = threadIdx.x;
  const int w   = t >> 6;            // wave id 0..7
  const int l   = t & 63;

  const float* xr = x + (size_t)blk * 533;
  const unsigned* nbd = nband + ((size_t)blk << 14);
  unsigned* wsrow = wsrows + ((size_t)blk << 14);

  __shared__ float2 FR[16][256];        // 32KB
  __shared__ float  magb[16*257];       // 16.4KB
  __shared__ float  phb[16*257];        // 16.4KB
  __shared__ float  resmag[257], resphase[257], msarr[257];
  __shared__ float2 carrybuf[2][128];
  __shared__ float2 hamtab[256];

  // ---- scalar params (block-uniform -> SGPRs) ----
  const float xc0 = clip01(xr[0]);
  const float xc1 = clip01(xr[1]);
  const float amp = clip01(xr[2]);
  const float mean = xc0 * 2.0f - 1.0f;
  const float stdv = xc1 * 0.1f;
  float mu_v = fminf(fmaxf(mean * 32768.0f, -16384.0f), 49152.0f);
  float sigma = fminf(fmaxf((1e-8f + stdv) * 32768.0f, 0.0f), 32767.0f);
  float K_v = -logf(sigma) - 0.91893853320467274f;
  float invsig_v = 1.0f / sigma;
  float istar = fminf(fmaxf(roundf(mu_v), 0.0f), 32767.0f);
  float ds0 = (istar - mu_v) * invsig_v;
  float emax = __expf(-0.5f * ds0 * ds0 + K_v);
  const float mu     = uniformf(mu_v);
  const float invsig = uniformf(invsig_v);
  const float K      = uniformf(K_v);
  const float gscale = uniformf(amp / (emax + 1e-8f));

  if (t < 257) {
    resmag[t]   = 0.01f + 0.99f * clip01(xr[3 + t]);
    resphase[t] = clip01(xr[260 + t]) * (2.0f*PI_F) - PI_F + (float)t * (PI_F / 512.0f);
    msarr[t]    = 0.0f;
  }
  if (t < 128) carrybuf[0][t] = make_float2(0.0f, 0.0f);
  if (t < 256) {
    const float W512 = 2.0f * PI_F / 512.0f;
    float n0 = (float)(2*t);
    hamtab[t] = make_float2(0.54f - 0.46f*__cosf(n0*W512),
                            0.54f - 0.46f*__cosf((n0+1.0f)*W512));
  }
  __syncthreads();

  // Hamming window pairs this lane will ever touch (fixed across groups/rows)
  const float2 hm0 = hamtab[l];
  const float2 hm1 = hamtab[l + 64];
  const float2 hm2 = hamtab[l + 128];
  const float2 hm3 = hamtab[l + 192];

  const float C2 = 0.044194173824159216f;   // 1/sqrt(512)
  const float F2 = 0.08838834764831845f;    // sqrt(512)/256
  const int iA = 2*w, iB = 2*w + 1;
  float2* rowA = FR[iA];
  float2* rowB = FR[iB];

  for (int g = 0; g < 8; ++g) {
    const int fgA = (g << 4) + iA;
    const int fgB = fgA + 1;

    // ---- (a) fused pack + forward stage J=64 (register butterfly) ----
    #pragma unroll
    for (int s = 0; s < 2; ++s) {
      float2* row = s ? rowB : rowA;
      const int base = (s ? fgB : fgA) << 7;
      float2 a0 = make_float2(0.f,0.f), a1 = a0, a2 = a0, a3 = a0;
      {
        int c0 = base + l;
        if (c0 < 16384) {
          float2 nb = unpack_h2(nbd[c0]);
          float s0 = (float)(2*c0);
          float d0 = (s0 - mu) * invsig, d1 = (s0 + 1.0f - mu) * invsig;
          a0 = make_float2(__expf(-0.5f*d0*d0 + K)*gscale*nb.x*hm0.x,
                           __expf(-0.5f*d1*d1 + K)*gscale*nb.y*hm0.y);
        }
        int c1 = base + l + 64;
        if (c1 < 16384) {
          float2 nb = unpack_h2(nbd[c1]);
          float s0 = (float)(2*c1);
          float d0 = (s0 - mu) * invsig, d1 = (s0 + 1.0f - mu) * invsig;
          a1 = make_float2(__expf(-0.5f*d0*d0 + K)*gscale*nb.x*hm1.x,
                           __expf(-0.5f*d1*d1 + K)*gscale*nb.y*hm1.y);
        }
        int c2 = base + l + 128;
        if (c2 < 16384) {
          float2 nb = unpack_h2(nbd[c2]);
          float s0 = (float)(2*c2);
          float d0 = (s0 - mu) * invsig, d1 = (s0 + 1.0f - mu) * invsig;
          a2 = make_float2(__expf(-0.5f*d0*d0 + K)*gscale*nb.x*hm2.x,
                           __expf(-0.5f*d1*d1 + K)*gscale*nb.y*hm2.y);
        }
        int c3 = base + l + 192;
        if (c3 < 16384) {
          float2 nb = unpack_h2(nbd[c3]);
          float s0 = (float)(2*c3);
          float d0 = (s0 - mu) * invsig, d1 = (s0 + 1.0f - mu) * invsig;
          a3 = make_float2(__expf(-0.5f*d0*d0 + K)*gscale*nb.x*hm3.x,
                           __expf(-0.5f*d1*d1 + K)*gscale*nb.y*hm3.y);
        }
      }
      float sn, cs; __sincosf((float)l * (-PI_F/128.0f), &sn, &cs);
      float2 w1 = make_float2(cs, sn), w2 = cmul(w1,w1), w3 = cmul(w2,w1);
      float2 t0 = cadd(a0,a2), t1 = cadd(a1,a3), t2 = csub(a0,a2), t3 = csub(a1,a3);
      float2 mi = make_float2(t3.y, -t3.x);
      row[swz8(l)]       = cadd(t0,t1);
      row[swz8(l+64)]    = cmul(cadd(t2,mi), w1);
      row[swz8(l+128)]   = cmul(csub(t0,t1), w2);
      row[swz8(l+192)]   = cmul(csub(t2,mi), w3);
    }
    LGKM();

    // ---- remaining forward stages (LDS) ----
    fr2_fwd(rowA, rowB, l, 16, 4); LGKM();
    fr2_fwd(rowA, rowB, l, 4, 2);  LGKM();
    fr2_fwd(rowA, rowB, l, 1, 0);  LGKM();

    // ---- magnitudes + phases -> magb/phb (FR untouched) ----
    if (l == 0) {
      #pragma unroll
      for (int s = 0; s < 2; ++s) {
        float2* row = s ? rowB : rowA;
        int ii = s ? iB : iA;
        float2 Z0 = row[0];
        float U0 = Z0.x + Z0.y, UM = Z0.x - Z0.y;
        magb[ii*257 + 0]   = fabsf(U0)*C2 + 1e-8f;
        magb[ii*257 + 256] = fabsf(UM)*C2 + 1e-8f;
        float2 Z = row[swz8(2)];           // self bin k=128 (dr8(128)=2)
        float2 U = make_float2(Z.x, -Z.y);
        float mC = sqrtf(U.x*U.x + U.y*U.y)*C2 + 1e-8f;
        magb[ii*257 + 128] = mC;
        phb[ii*257 + 128]  = (U.y*C2/mC)*PI_F;
      }
    } else {
      int pk = swz8(dr8(l)), pm = swz8(dr8(256 - l));
      float sn, cs; __sincosf((float)l * (PI_F/256.0f), &sn, &cs);
      #pragma unroll
      for (int s = 0; s < 2; ++s) {
        float2* row = s ? rowB : rowA;
        int ii = s ? iB : iA;
        float2 Uk, Um; unpack_pair(row[pk], row[pm], sn, cs, Uk, Um);
        float mk = sqrtf(Uk.x*Uk.x + Uk.y*Uk.y)*C2 + 1e-8f;
        float mm = sqrtf(Um.x*Um.x + Um.y*Um.y)*C2 + 1e-8f;
        magb[ii*257 + l]     = mk;
        magb[ii*257 + 256-l] = mm;
        phb[ii*257 + l]      = (Uk.y*C2/mk)*PI_F;
        phb[ii*257 + 256-l]  = (Um.y*C2/mm)*PI_F;
      }
    }
    {
      const int kB = l + 64;
      int pk = swz8(dr8(kB)), pm = swz8(dr8(256 - kB));
      float sn, cs; __sincosf((float)kB * (PI_F/256.0f), &sn, &cs);
      #pragma unroll
      for (int s = 0; s < 2; ++s) {
        float2* row = s ? rowB : rowA;
        int ii = s ? iB : iA;
        float2 Uk, Um; unpack_pair(row[pk], row[pm], sn, cs, Uk, Um);
        float mk = sqrtf(Uk.x*Uk.x + Uk.y*Uk.y)*C2 + 1e-8f;
        float mm = sqrtf(Um.x*Um.x + Um.y*Um.y)*C2 + 1e-8f;
        magb[ii*257 + kB]     = mk;
        magb[ii*257 + 256-kB] = mm;
        phb[ii*257 + kB]      = (Uk.y*C2/mk)*PI_F;
        phb[ii*257 + 256-kB]  = (Um.y*C2/mm)*PI_F;
      }
    }
    __syncthreads();

    // ---- sequential magnitude scan across the 16 frames (per bin) ----
    if (t < 257) {
      float rm = resmag[t], r = msarr[t];
      float mg[16];
      #pragma unroll
      for (int i = 0; i < 16; ++i) mg[i] = magb[i*257 + t];
      #pragma unroll
      for (int i = 0; i < 16; ++i) {
        r = fmaf(rm, r, mg[i]);
        magb[i*257 + t] = r;
      }
      msarr[t] = r;
    }
    __syncthreads();

    // ---- rebuild from scanned mag + stored phase, repack ----
    {
      const float fmA = (fgA > 0) ? 1.0f : 0.0f;   // fgB >= 1 always -> fm=1
      if (l == 0) {
        #pragma unroll
        for (int s = 0; s < 2; ++s) {
          float2* row = s ? rowB : rowA;
          int ii = s ? iB : iA;
          float fm = s ? 1.0f : fmA;
          float ms0 = magb[ii*257 + 0]   * F2;
          float msM = magb[ii*257 + 256] * F2;
          float V0 = ms0 * __cosf(fm*resphase[0]);
          float VM = msM * __cosf(fm*resphase[256]);
          row[0] = make_float2(0.5f*(V0+VM), 0.5f*(V0-VM));
          float msC = magb[ii*257 + 128] * F2;
          float pC  = phb[ii*257 + 128] + fm*resphase[128];
          float sC, cC; __sincosf(pC, &sC, &cC);
          row[swz8(2)] = make_float2(msC*cC, -(msC*sC));
        }
      } else {
        int pk = swz8(dr8(l)), pm = swz8(dr8(256 - l));
        float sn, cs; __sincosf((float)l * (PI_F/256.0f), &sn, &cs);
        float rp1 = resphase[l], rp2 = resphase[256-l];
        #pragma unroll
        for (int s = 0; s < 2; ++s) {
          float2* row = s ? rowB : rowA;
          int ii = s ? iB : iA;
          float fm = s ? 1.0f : fmA;
          float msk = magb[ii*257 + l]     * F2;
          float msm = magb[ii*257 + 256-l] * F2;
          float p1 = phb[ii*257 + l]     + fm*rp1;
          float p2 = phb[ii*257 + 256-l] + fm*rp2;
          float s1,c1,s2,c2; __sincosf(p1,&s1,&c1); __sincosf(p2,&s2,&c2);
          float2 Vk = make_float2(msk*c1, msk*s1);
          float2 Vm = make_float2(msm*c2, msm*s2);
          float2 Wk, Wm; repack_pair(Vk, Vm, sn, cs, Wk, Wm);
          row[pk] = Wk; row[pm] = Wm;
        }
      }
      {
        const int kB = l + 64;
        int pk = swz8(dr8(kB)), pm = swz8(dr8(256 - kB));
        float sn, cs; __sincosf((float)kB * (PI_F/256.0f), &sn, &cs);
        float rp1 = resphase[kB], rp2 = resphase[256-kB];
        #pragma unroll
        for (int s = 0; s < 2; ++s) {
          float2* row = s ? rowB : rowA;
          int ii = s ? iB : iA;
          float fm = s ? 1.0f : fmA;
          float msk = magb[ii*257 + kB]     * F2;
          float msm = magb[ii*257 + 256-kB] * F2;
          float p1 = phb[ii*257 + kB]     + fm*rp1;
          float p2 = phb[ii*257 + 256-kB] + fm*rp2;
          float s1,c1,s2,c2; __sincosf(p1,&s1,&c1); __sincosf(p2,&s2,&c2);
          float2 Vk = make_float2(msk*c1, msk*s1);
          float2 Vm = make_float2(msm*c2, msm*s2);
          float2 Wk, Wm; repack_pair(Vk, Vm, sn, cs, Wk, Wm);
          row[pk] = Wk; row[pm] = Wm;
        }
      }
      LGKM();
      fr2_inv(rowA, rowB, l, 1, 0);  LGKM();
      fr2_inv(rowA, rowB, l, 4, 2);  LGKM();
      fr2_inv(rowA, rowB, l, 16, 4); LGKM();
      fr2_inv(rowA, rowB, l, 64, 6);
    }
    __syncthreads();

    // ---- overlap-add emit: 2048 pair slots / 512 threads = 4 reps ----
    #pragma unroll
    for (int rep = 0; rep < 4; ++rep) {
      int slot = t + (rep << 9);
      int i = slot >> 7, j = slot & 127;
      int fg = (g << 4) + i;
      float2 first  = FR[i][swz8(j)];
      float2 second = (i > 0) ? FR[i-1][swz8(128 + j)] : carrybuf[g & 1][j];
      float2 v = cadd(first, second);
      wsrow[(fg << 7) + j] = pack_h2(v.x, v.y);
      if (i == 15) {  // save carry for next group (double-buffered)
        carrybuf[(g & 1) ^ 1][j] = FR[15][swz8(128 + j)];
      }
    }
    __syncthreads();
  }
}

// ================= MONO fallback (round-5 kernel, proven, f32) ===============
__global__ void __launch_bounds__(1024, 4)
atoms_main(const float* __restrict__ x, const float* __restrict__ noise,
           float* __restrict__ outacc, float2* __restrict__ wsbuf, int use_ws) {
  const int blk = blockIdx.x;
  const int b   = blk >> 4;
  const int t   = threadIdx.x;
  const int w   = t >> 6;
  const int l   = t & 63;

  const float* xr = x + (size_t)blk * 533;
  const float* nr = noise + (size_t)blk * 32768;

  __shared__ float2 Cs[16384];
  __shared__ float2 FR[8][256];
  __shared__ float  magb[8*257];
  __shared__ float  resmag[257], resphase[257], msarr[257];
  __shared__ float2 carrybuf[2][128];
  __shared__ float2 hamtab[256];
  __shared__ float  ncs[16];

  const float xc0 = clip01(xr[0]);
  const float xc1 = clip01(xr[1]);
  const float amp = clip01(xr[2]);
  const float mean = xc0 * 2.0f - 1.0f;
  const float stdv = xc1 * 0.1f;
  float mu_v = fminf(fmaxf(mean * 32768.0f, -16384.0f), 49152.0f);
  float sigma = fminf(fmaxf((1e-8f + stdv) * 32768.0f, 0.0f), 32767.0f);
  float K_v = -logf(sigma) - 0.91893853320467274f;
  float invsig_v = 1.0f / sigma;
  float istar = fminf(fmaxf(roundf(mu_v), 0.0f), 32767.0f);
  float ds0 = (istar - mu_v) * invsig_v;
  float emax = __expf(-0.5f * ds0 * ds0 + K_v);
  const float mu     = uniformf(mu_v);
  const float invsig = uniformf(invsig_v);
  const float K      = uniformf(K_v);
  const float gscale = uniformf(amp / (emax + 1e-8f));

  if (t < 257) {
    resmag[t]   = 0.01f + 0.99f * clip01(xr[3 + t]);
    resphase[t] = clip01(xr[260 + t]) * (2.0f*PI_F) - PI_F + (float)t * (PI_F / 512.0f);
    msarr[t]    = 0.0f;
  }
  if (t < 16)  ncs[t] = clip01(xr[517 + t]);
  if (t < 128) carrybuf[0][t] = make_float2(0.0f, 0.0f);
  if (t < 256) {
    const float W512 = 2.0f * PI_F / 512.0f;
    float n0 = (float)(2*t);
    hamtab[t] = make_float2(0.54f - 0.46f*__cosf(n0*W512),
                            0.54f - 0.46f*__cosf((n0+1.0f)*W512));
  }

  {
    const float4* nr4 = (const float4*)nr;
    #pragma unroll
    for (int i2 = 0; i2 < 8; ++i2) {
      int m = t + (i2 << 10);
      float4 v4 = nr4[m];
      Cs[swz14(2*m)]   = make_float2(v4.x*2.0f-1.0f, v4.y*2.0f-1.0f);
      Cs[swz14(2*m+1)] = make_float2(v4.z*2.0f-1.0f, v4.w*2.0f-1.0f);
    }
  }
  __syncthreads();

  const int ub = ((t >> 6) << 8) + (t & 63);

  #pragma unroll
  for (int r = 0; r < 4; ++r) big_stage_fwd(Cs, ub + (r<<6), 4096, 12);
  __syncthreads();
  #pragma unroll
  for (int r = 0; r < 4; ++r) big_stage_fwd(Cs, ub + (r<<6), 1024, 10);
  __syncthreads();
  #pragma unroll
  for (int r = 0; r < 4; ++r) big_stage_fwd(Cs, ub + (r<<6), 256, 8);
  LGKM();
  #pragma unroll
  for (int r = 0; r < 4; ++r) big_stage_fwd(Cs, ub + (r<<6), 64, 6);
  LGKM();
  #pragma unroll
  for (int r = 0; r < 4; ++r) big_stage_fwd(Cs, ub + (r<<6), 16, 4);
  LGKM();
  #pragma unroll
  for (int r = 0; r < 4; ++r) big_stage_fwd(Cs, ub + (r<<6), 4, 2);
  LGKM();
  #pragma unroll
  for (int r = 0; r < 4; ++r) big_stage_fwd(Cs, ub + (r<<6), 1, 0);
  __syncthreads();

  {
    const float invM = 1.0f / 16384.0f;
    for (int k = t; k < 8192; k += 1024) {
      if (k == 0) {
        float2 Z0 = Cs[0];
        float U0 = Z0.x + Z0.y;
        float UM = Z0.x - Z0.y;
        float V0 = U0 * sshape(0, ncs) * invM;
        float VM = UM * sshape(16384, ncs) * invM;
        Cs[0] = make_float2(0.5f*(V0+VM), 0.5f*(V0-VM));
      } else {
        int pk = swz14(dr14(k));
        int pm = swz14(dr14(16384 - k));
        float2 Zk = Cs[pk], Zm = Cs[pm];
        float sn, cs; __sincosf((float)k * (PI_F / 16384.0f), &sn, &cs);
        float2 Uk, Um; unpack_pair(Zk, Zm, sn, cs, Uk, Um);
        float2 Vk = cscale(Uk, sshape(k, ncs) * invM);
        float2 Vm = cscale(Um, sshape(16384 - k, ncs) * invM);
        float2 Wk, Wm; repack_pair(Vk, Vm, sn, cs, Wk, Wm);
        Cs[pk] = Wk; Cs[pm] = Wm;
      }
    }
    if (t == 0) {
      int p = swz14(2);
      float2 Z = Cs[p];
      float2 U = make_float2(Z.x, -Z.y);
      float2 V = cscale(U, sshape(8192, ncs) * (1.0f/16384.0f));
      Cs[p] = make_float2(V.x, -V.y);
    }
  }
  __syncthreads();

  #pragma unroll
  for (int r = 0; r < 4; ++r) big_stage_inv(Cs, ub + (r<<6), 1, 0);
  LGKM();
  #pragma unroll
  for (int r = 0; r < 4; ++r) big_stage_inv(Cs, ub + (r<<6), 4, 2);
  LGKM();
  #pragma unroll
  for (int r = 0; r < 4; ++r) big_stage_inv(Cs, ub + (r<<6), 16, 4);
  LGKM();
  #pragma unroll
  for (int r = 0; r < 4; ++r) big_stage_inv(Cs, ub + (r<<6), 64, 6);
  LGKM();
  #pragma unroll
  for (int r = 0; r < 4; ++r) big_stage_inv(Cs, ub + (r<<6), 256, 8);
  __syncthreads();
  #pragma unroll
  for (int r = 0; r < 4; ++r) big_stage_inv(Cs, ub + (r<<6), 1024, 10);
  __syncthreads();
  #pragma unroll
  for (int r = 0; r < 4; ++r) big_stage_inv(Cs, ub + (r<<6), 4096, 12);
  __syncthreads();

  const float C2 = 0.044194173824159216f;
  const float F2 = 0.08838834764831845f;
  float2* row = (w < 8) ? FR[w] : FR[0];
  float2* wsrow = use_ws ? (wsbuf + ((size_t)blk << 14)) : (float2*)0;

  for (int g = 0; g < 16; ++g) {
    #pragma unroll
    for (int rep = 0; rep < 2; ++rep) {
      int slot = t + (rep << 10);
      int i = slot >> 8, j = slot & 255;
      int fg = (g << 3) + i;
      int cidx = (fg << 7) + j;
      float2 v = make_float2(0.0f, 0.0f);
      if (cidx < 16384) {
        float2 nb = Cs[swz14(cidx)];
        float s0 = (float)(2*cidx);
        float d0 = (s0 - mu) * invsig;
        float d1 = (s0 + 1.0f - mu) * invsig;
        float2 h = hamtab[j];
        v = make_float2(__expf(-0.5f*d0*d0 + K) * gscale * nb.x * h.x,
                        __expf(-0.5f*d1*d1 + K) * gscale * nb.y * h.y);
      }
      FR[i][swz8(j)] = v;
    }
    __syncthreads();

    if (w < 8) {
      fr_stage_fwd(row, l, 64, 6); LGKM();
      fr_stage_fwd(row, l, 16, 4); LGKM();
      fr_stage_fwd(row, l, 4, 2);  LGKM();
      fr_stage_fwd(row, l, 1, 0);  LGKM();

      if (l == 0) {
        float2 Z0 = row[0];
        float U0 = Z0.x + Z0.y, UM = Z0.x - Z0.y;
        magb[w*257 + 0]   = fabsf(U0)*C2 + 1e-8f;
        magb[w*257 + 256] = fabsf(UM)*C2 + 1e-8f;
        float2 Z = row[swz8(2)];
        magb[w*257 + 128] = sqrtf(Z.x*Z.x + Z.y*Z.y)*C2 + 1e-8f;
      } else {
        int pk = swz8(dr8(l)), pm = swz8(dr8(256 - l));
        float sn, cs; __sincosf((float)l * (PI_F/256.0f), &sn, &cs);
        float2 Uk, Um; unpack_pair(row[pk], row[pm], sn, cs, Uk, Um);
        magb[w*257 + l]     = sqrtf(Uk.x*Uk.x + Uk.y*Uk.y)*C2 + 1e-8f;
        magb[w*257 + 256-l] = sqrtf(Um.x*Um.x + Um.y*Um.y)*C2 + 1e-8f;
      }
      {
        const int kB = l + 64;
        int pk = swz8(dr8(kB)), pm = swz8(dr8(256 - kB));
        float sn, cs; __sincosf((float)kB * (PI_F/256.0f), &sn, &cs);
        float2 Uk, Um; unpack_pair(row[pk], row[pm], sn, cs, Uk, Um);
        magb[w*257 + kB]     = sqrtf(Uk.x*Uk.x + Uk.y*Uk.y)*C2 + 1e-8f;
        magb[w*257 + 256-kB] = sqrtf(Um.x*Um.x + Um.y*Um.y)*C2 + 1e-8f;
      }
    }
    __syncthreads();

    if (t < 257) {
      float rm = resmag[t], r = msarr[t];
      #pragma unroll
      for (int i = 0; i < 8; ++i) {
        float mg = magb[i*257 + t];
        r = fmaf(rm, r, mg);
        magb[i*257 + t] = r;
      }
      msarr[t] = r;
    }
    __syncthreads();

    if (w < 8) {
      float fm = ((g << 3) + w > 0) ? 1.0f : 0.0f;
      if (l == 0) {
        float ms0 = magb[w*257 + 0]   * F2;
        float msM = magb[w*257 + 256] * F2;
        float V0 = ms0 * __cosf(fm*resphase[0]);
        float VM = msM * __cosf(fm*resphase[256]);
        row[0] = make_float2(0.5f*(V0+VM), 0.5f*(V0-VM));
        float2 Z = row[swz8(2)];
        float2 U = make_float2(Z.x, -Z.y);
        float mC = sqrtf(U.x*U.x + U.y*U.y)*C2 + 1e-8f;
        float pC = (U.y*C2/mC)*PI_F + fm*resphase[128];
        float msC = magb[w*257 + 128] * F2;
        float sC, cC; __sincosf(pC, &sC, &cC);
        row[swz8(2)] = make_float2(msC*cC, -(msC*sC));
      } else {
        int pk = swz8(dr8(l)), pm = swz8(dr8(256 - l));
        float sn, cs; __sincosf((float)l * (PI_F/256.0f), &sn, &cs);
        float2 Uk, Um; unpack_pair(row[pk], row[pm], sn, cs, Uk, Um);
        float mk = sqrtf(Uk.x*Uk.x + Uk.y*Uk.y)*C2 + 1e-8f;
        float mm = sqrtf(Um.x*Um.x + Um.y*Um.y)*C2 + 1e-8f;
        float p1 = (Uk.y*C2/mk)*PI_F + fm*resphase[l];
        float p2 = (Um.y*C2/mm)*PI_F + fm*resphase[256-l];
        float msk = magb[w*257 + l]     * F2;
        float msm = magb[w*257 + 256-l] * F2;
        float s1,c1,s2,c2; __sincosf(p1,&s1,&c1); __sincosf(p2,&s2,&c2);
        float2 Vk = make_float2(msk*c1, msk*s1);
        float2 Vm = make_float2(msm*c2, msm*s2);
        float2 Wk, Wm; repack_pair(Vk, Vm, sn, cs, Wk, Wm);
        row[pk] = Wk; row[pm] = Wm;
      }
      {
        const int kB = l + 64;
        int pk = swz8(dr8(kB)), pm = swz8(dr8(256 - kB));
        float sn, cs; __sincosf((float)kB * (PI_F/256.0f), &sn, &cs);
        float2 Uk, Um; unpack_pair(row[pk], row[pm], sn, cs, Uk, Um);
        float mk = sqrtf(Uk.x*Uk.x + Uk.y*Uk.y)*C2 + 1e-8f;
        float mm = sqrtf(Um.x*Um.x + Um.y*Um.y)*C2 + 1e-8f;
        float p1 = (Uk.y*C2/mk)*PI_F + fm*resphase[kB];
        float p2 = (Um.y*C2/mm)*PI_F + fm*resphase[256-kB];
        float msk = magb[w*257 + kB]     * F2;
        float msm = magb[w*257 + 256-kB] * F2;
        float s1,c1,s2,c2; __sincosf(p1,&s1,&c1); __sincosf(p2,&s2,&c2);
        float2 Vk = make_float2(msk*c1, msk*s1);
        float2 Vm = make_float2(msm*c2, msm*s2);
        float2 Wk, Wm; repack_pair(Vk, Vm, sn, cs, Wk, Wm);
        row[pk] = Wk; row[pm] = Wm;
      }
      LGKM();
      fr_stage_inv(row, l, 1, 0);  LGKM();
      fr_stage_inv(row, l, 4, 2);  LGKM();
      fr_stage_inv(row, l, 16, 4); LGKM();
      fr_stage_inv(row, l, 64, 6);
    }
    __syncthreads();

    {
      int i = t >> 7, j = t & 127;
      int fg = (g << 3) + i;
      float2 first  = FR[i][swz8(j)];
      float2 second = (i > 0) ? FR[i-1][swz8(128 + j)] : carrybuf[g & 1][j];
      float2 v = cadd(first, second);
      if (use_ws) {
        wsrow[(fg << 7) + j] = v;
      } else {
        float* dst = outacc + (size_t)b*32768 + (fg << 8) + 2*j;
        atomicAdd(dst,     v.x);
        atomicAdd(dst + 1, v.y);
      }
      if (i == 7) {
        carrybuf[(g & 1) ^ 1][j] = FR[7][swz8(128 + j)];
      }
    }
    __syncthreads();
  }
}

// ---------- ws path: sum 16 events + segment max (half rows) ----------
__global__ void __launch_bounds__(1024, 1)
atoms_sum_max_h(const unsigned* __restrict__ ws, float* __restrict__ out, float* __restrict__ wmax) {
  int blk = blockIdx.x;               // 256 = 32 b x 8 seg
  int b = blk >> 3, seg = blk & 7, tid = threadIdx.x;
  const unsigned* base = ws + (size_t)b*16*16384 + (size_t)seg*2048;
  float2 v[2]; float m = 0.0f;
  #pragma unroll
  for (int i = 0; i < 2; ++i) {
    int idx = tid + (i << 10);
    float2 s = make_float2(0.0f, 0.0f);
    #pragma unroll
    for (int e = 0; e < 16; ++e) {
      float2 u = unpack_h2(base[(size_t)e*16384 + idx]);
      s.x += u.x; s.y += u.y;
    }
    v[i] = s;
    m = fmaxf(m, fmaxf(fabsf(s.x), fabsf(s.y)));
  }
  float2* op = (float2*)(out + (size_t)b*32768 + (seg << 12));
  #pragma unroll
  for (int i = 0; i < 2; ++i) op[tid + (i << 10)] = v[i];
  __shared__ float red[1024];
  red[tid] = m; __syncthreads();
  for (int s2 = 512; s2 > 0; s2 >>= 1) {
    if (tid < s2) red[tid] = fmaxf(red[tid], red[tid + s2]);
    __syncthreads();
  }
  if (tid == 0) wmax[blk] = red[0];
}

// ---------- ws path: sum 16 events + segment max (f32 rows, fallback) --------
__global__ void __launch_bounds__(1024, 1)
atoms_sum_max(const float* __restrict__ ws, float* __restrict__ out, float* __restrict__ wmax) {
  int blk = blockIdx.x;               // 256 = 32 b x 8 seg
  int b = blk >> 3, seg = blk & 7, tid = threadIdx.x;
  const float* base = ws + (size_t)b*16*32768 + (size_t)seg*4096;
  float v[4]; float m = 0.0f;
  #pragma unroll
  for (int i = 0; i < 4; ++i) {
    int idx = (i << 10) + tid;
    float s = 0.0f;
    #pragma unroll
    for (int e = 0; e < 16; ++e) s += base[(size_t)e*32768 + idx];
    v[i] = s; m = fmaxf(m, fabsf(s));
  }
  float* op = out + (size_t)b*32768 + (seg << 12);
  #pragma unroll
  for (int i = 0; i < 4; ++i) op[(i<<10) + tid] = v[i];
  __shared__ float red[1024];
  red[tid] = m; __syncthreads();
  for (int s2 = 512; s2 > 0; s2 >>= 1) {
    if (tid < s2) red[tid] = fmaxf(red[tid], red[tid + s2]);
    __syncthreads();
  }
  if (tid == 0) wmax[blk] = red[0];
}

__global__ void __launch_bounds__(1024, 1)
atoms_scale(float* __restrict__ out, const float* __restrict__ wmax) {
  int blk = blockIdx.x;
  int b = blk >> 3, seg = blk & 7, tid = threadIdx.x;
  const float* wm = wmax + b*8;
  float m = fmaxf(fmaxf(fmaxf(wm[0],wm[1]), fmaxf(wm[2],wm[3])),
                  fmaxf(fmaxf(wm[4],wm[5]), fmaxf(wm[6],wm[7])));
  float inv = 1.0f / (m + 1e-8f);
  float* op = out + (size_t)b*32768 + (seg << 12);
  #pragma unroll
  for (int i = 0; i < 4; ++i) op[(i<<10) + tid] *= inv;
}

// ---------- atomic-path fallback norm ----------
__global__ void __launch_bounds__(1024, 1)
atoms_norm(float* __restrict__ out) {
  const int b = blockIdx.x;
  const int tid = threadIdx.x;
  float* p = out + (size_t)b * 32768;
  __shared__ float red[1024];
  float m = 0.0f;
  for (int i = tid; i < 32768; i += 1024) m = fmaxf(m, fabsf(p[i]));
  red[tid] = m;
  __syncthreads();
  for (int s = 512; s > 0; s >>= 1) {
    if (tid < s) red[tid] = fmaxf(red[tid], red[tid + s]);
    __syncthreads();
  }
  const float inv = 1.0f / (red[0] + 1e-8f);
  for (int i = tid; i < 32768; i += 1024) p[i] = p[i] * inv;
}

extern "C" void kernel_launch(void* const* d_in, const int* in_sizes, int n_in,
                              void* d_out, int out_size, void* d_ws, size_t ws_size,
                              hipStream_t stream) {
  (void)in_sizes; (void)n_in; (void)out_size;
  const float* x     = (const float*)d_in[0];
  const float* noise = (const float*)d_in[1];
  float* out = (float*)d_out;

  const size_t pairs_u    = 512ull * 16384ull;                // pairs per buffer (u32 each)
  const size_t rows_f     = 512ull * 32768ull;                // f32 rows (fallback)
  const size_t need_ws    = rows_f*4 + 4096;                  // f32 rows + wmax (fallback)
  const size_t need_split = pairs_u*4 + 4096 + pairs_u*4;     // half rows + wmax + half nband

  if (d_ws != nullptr && ws_size >= need_split) {
    unsigned* ws_u = (unsigned*)d_ws;
    float*    wmax = (float*)(ws_u + pairs_u);
    unsigned* nbd  = ws_u + pairs_u + 1024;
    atoms_noise <<<512, 1024, 0, stream>>>(x, noise, nbd);
    atoms_frames<<<512,  512, 0, stream>>>(x, nbd, ws_u);
    atoms_sum_max_h<<<256, 1024, 0, stream>>>(ws_u, out, wmax);
    atoms_scale<<<256, 1024, 0, stream>>>(out, wmax);
  } else if (d_ws != nullptr && ws_size >= need_ws) {
    float* ws = (float*)d_ws;
    float* wmax = ws + rows_f;
    atoms_main<<<512, 1024, 0, stream>>>(x, noise, nullptr, (float2*)ws, 1);
    atoms_sum_max<<<256, 1024, 0, stream>>>(ws, out, wmax);
    atoms_scale<<<256, 1024, 0, stream>>>(out, wmax);
  } else {
    atoms_zero<<<1024, 1024, 0, stream>>>(out);
    atoms_main<<<512, 1024, 0, stream>>>(x, noise, out, nullptr, 0);
    atoms_norm<<<32, 1024, 0, stream>>>(out);
  }
}